// Round 11
// baseline (1265.678 us; speedup 1.0000x reference)
//
#include <hip/hip_runtime.h>

typedef unsigned short u16;
typedef __attribute__((ext_vector_type(8))) short s8v;
typedef __attribute__((ext_vector_type(4))) float f4v;

__device__ __forceinline__ u16 f2bf(float f) {
  unsigned int x = __float_as_uint(f);
  return (u16)((x + 0x7fffu + ((x >> 16) & 1u)) >> 16);
}
__device__ __forceinline__ float bf2f(u16 u) {
  return __uint_as_float(((unsigned int)u) << 16);
}

// ---------------------------------------------------------------------------
struct Epi {
  const float* bias;
  const u16* r1; int r1Hp, r1pad, r1sh;   // residual adds (C=256 NHWC)
  const u16* r2; int r2Hp, r2pad, r2sh;
  const float* gamma; const u16* other; int oHp, opad, gmode; // 1: g*o+(1-g)*v ; 2: g*v+(1-g)*o
  u16* outB; int oBHp, oBpad, oBrelu;     // bf16 NHWC out (C=M)
  float* outF;                             // fp32 NCHW out
};

__device__ __forceinline__ size_t nhwc_idx(int b, int h, int w, int Hp, int pad, int Cc, int m) {
  return (((size_t)(b * Hp + h + pad)) * Hp + (w + pad)) * Cc + m;
}

// scalar path (k_red)
__device__ __forceinline__ void epi_apply_store(float v, int m, int b, int oh, int ow,
                                                int p, int M, int l2ohow, float g, const Epi& ep) {
  if (ep.bias) v += ep.bias[m];
  if (ep.r1) v += bf2f(ep.r1[nhwc_idx(b, oh >> ep.r1sh, ow >> ep.r1sh, ep.r1Hp, ep.r1pad, 256, m)]);
  if (ep.r2) v += bf2f(ep.r2[nhwc_idx(b, oh >> ep.r2sh, ow >> ep.r2sh, ep.r2Hp, ep.r2pad, 256, m)]);
  if (ep.gmode) {
    float o = bf2f(ep.other[nhwc_idx(b, oh, ow, ep.oHp, ep.opad, 256, m)]);
    v = (ep.gmode == 1) ? (g * o + (1.f - g) * v) : (g * v + (1.f - g) * o);
  }
  if (ep.outF) ep.outF[(((size_t)(b * M + m)) << l2ohow) + p] = v;
  if (ep.outB) {
    float w = ep.oBrelu ? fmaxf(v, 0.f) : v;
    ep.outB[nhwc_idx(b, oh, ow, ep.oBHp, ep.oBpad, M, m)] = f2bf(w);
  }
}

// vector path (gemm FUSE): 4 consecutive m per call, packed ushort4 store
__device__ __forceinline__ void epi4(f4v a, int mbase, int b, int oh, int ow,
                                     int p, int M, int l2ohow, float g, const Epi& ep) {
  float v[4];
#pragma unroll
  for (int r = 0; r < 4; ++r) v[r] = a[r];
  if (ep.bias) {
    const float* bp = &ep.bias[mbase];
#pragma unroll
    for (int r = 0; r < 4; ++r) v[r] += bp[r];
  }
  if (ep.r1) {
    const u16* rp = &ep.r1[nhwc_idx(b, oh >> ep.r1sh, ow >> ep.r1sh, ep.r1Hp, ep.r1pad, 256, mbase)];
#pragma unroll
    for (int r = 0; r < 4; ++r) v[r] += bf2f(rp[r]);
  }
  if (ep.r2) {
    const u16* rp = &ep.r2[nhwc_idx(b, oh >> ep.r2sh, ow >> ep.r2sh, ep.r2Hp, ep.r2pad, 256, mbase)];
#pragma unroll
    for (int r = 0; r < 4; ++r) v[r] += bf2f(rp[r]);
  }
  if (ep.gmode) {
    const u16* op = &ep.other[nhwc_idx(b, oh, ow, ep.oHp, ep.opad, 256, mbase)];
#pragma unroll
    for (int r = 0; r < 4; ++r) {
      float o = bf2f(op[r]);
      v[r] = (ep.gmode == 1) ? (g * o + (1.f - g) * v[r]) : (g * v[r] + (1.f - g) * o);
    }
  }
  if (ep.outF) {
    float* fp = &ep.outF[(((size_t)(b * M + mbase)) << l2ohow) + p];
#pragma unroll
    for (int r = 0; r < 4; ++r) fp[(size_t)r << l2ohow] = v[r];
  }
  if (ep.outB) {
    u16* obp = &ep.outB[nhwc_idx(b, oh, ow, ep.oBHp, ep.oBpad, M, mbase)];
    ushort4 pk;
    if (ep.oBrelu) { pk.x = f2bf(fmaxf(v[0], 0.f)); pk.y = f2bf(fmaxf(v[1], 0.f));
                     pk.z = f2bf(fmaxf(v[2], 0.f)); pk.w = f2bf(fmaxf(v[3], 0.f)); }
    else { pk.x = f2bf(v[0]); pk.y = f2bf(v[1]); pk.z = f2bf(v[2]); pk.w = f2bf(v[3]); }
    *(ushort4*)obp = pk;
  }
}

// ---------------------------------------------------------------------------
// Weight convert/reorder, one block per (segment, m, ktile), 1 elem/thread.
// ---------------------------------------------------------------------------
struct WSeg { const float* src; u16* dst; int K, l2Cin, mode, ktiles, blk0; };
struct WTab { WSeg s[17]; };

__global__ __launch_bounds__(256) void k_cvt_w(WTab tab) {
  int bid = blockIdx.x;
  int si = 0;
#pragma unroll
  for (int i = 1; i < 17; ++i) si += (bid >= tab.s[i].blk0) ? 1 : 0;
  WSeg sg = tab.s[si];
  int rel = bid - sg.blk0;
  int m = rel / sg.ktiles;
  int kt = rel - m * sg.ktiles;
  int r = kt * 256 + threadIdx.x;
  if (r >= sg.K) return;
  int Cin = 1 << sg.l2Cin;
  int q = r >> sg.l2Cin, c = r & (Cin - 1);
  int sidx;
  if (sg.mode == 1) {
    int og = (q < 4) ? (q + 1) : 0;
    sidx = m * sg.K + og * Cin + c;
  } else {
    int KHW = sg.K >> sg.l2Cin;
    sidx = (m * Cin + c) * KHW + q;
  }
  sg.dst[(size_t)m * sg.K + r] = f2bf(sg.src[sidx]);
}

// ---------------------------------------------------------------------------
// NCHW fp32 -> NHWC bf16 (optional pad), LDS 32x32 transpose tiles.
// ---------------------------------------------------------------------------
__global__ __launch_bounds__(256) void k_cvt_x(const float* __restrict__ in, u16* __restrict__ out,
                                               int C, int H, int W, int Hp, int P, int tw) {
  __shared__ u16 tile[32][33];
  const int t = threadIdx.x;
  const int b = blockIdx.z, h = blockIdx.y;
  const int tc = blockIdx.x / tw, twi = blockIdx.x - tc * tw;
  const int c0 = tc * 32, w0 = twi * 32;
#pragma unroll
  for (int r = 0; r < 4; ++r) {
    int cl = (t >> 5) * 4 + r, wl = t & 31;
    if (w0 + wl < W) tile[cl][wl] = f2bf(in[(((size_t)b * C + c0 + cl) * H + h) * W + w0 + wl]);
  }
  __syncthreads();
#pragma unroll
  for (int r = 0; r < 4; ++r) {
    int wl = (t >> 5) * 4 + r, cl = t & 31;
    if (w0 + wl < W) out[(((size_t)(b * Hp + h + P)) * Hp + (w0 + wl + P)) * C + c0 + cl] = tile[cl][wl];
  }
}

// ---------------------------------------------------------------------------
// Cummax scans, coalesced NCHW bf16 out[g][b*C+c][S*S].
// ---------------------------------------------------------------------------
template<int S, int L2S>
__global__ __launch_bounds__(256) void k_scan2(const float* __restrict__ x,
                                               u16* __restrict__ out, int l2C) {
  __shared__ u16 pl[S][S + 1], rp[S][S + 1], rs[S][S + 1];
  const int pid = blockIdx.x;
  const size_t SS = (size_t)S * S;
  const size_t GS = ((size_t)8 << l2C) * SS;
  const float* xp = x + (size_t)pid * SS;
  u16* g0 = out + (size_t)pid * SS;
  u16* g1 = g0 + GS;
  u16* g2 = g1 + GS;
  u16* g3 = g2 + GS;
  const int t = threadIdx.x;
  for (int idx = t; idx < S * S; idx += 256)
    pl[idx >> L2S][idx & (S - 1)] = f2bf(xp[idx]);
  __syncthreads();
  if (t < S) {
    float m = -INFINITY;
    for (int h = 0; h < S; ++h) { m = fmaxf(m, bf2f(pl[h][t])); g0[h * S + t] = f2bf(m); }
  } else if (t < 2 * S) {
    int c = t - S;
    float m = -INFINITY;
    for (int h = S - 1; h >= 0; --h) { m = fmaxf(m, bf2f(pl[h][c])); g1[h * S + c] = f2bf(m); }
  } else if (t < 3 * S) {
    int h = t - 2 * S;
    float m = -INFINITY;
    for (int w = 0; w < S; ++w) { m = fmaxf(m, bf2f(pl[h][w])); rp[h][w] = f2bf(m); }
  } else if (t < 4 * S) {
    int h = t - 3 * S;
    float m = -INFINITY;
    for (int w = S - 1; w >= 0; --w) { m = fmaxf(m, bf2f(pl[h][w])); rs[h][w] = f2bf(m); }
  }
  __syncthreads();
  for (int idx = t; idx < S * S; idx += 256) {
    g2[idx] = rp[idx >> L2S][idx & (S - 1)];
    g3[idx] = rs[idx >> L2S][idx & (S - 1)];
  }
}

// ---------------------------------------------------------------------------
// bf16 NCHW -> NHWC transpose. src[z][C][S*S] -> dst[z][S*S][C], z = g*8+b.
// ---------------------------------------------------------------------------
__global__ __launch_bounds__(256) void k_tr(const u16* __restrict__ src, u16* __restrict__ dst,
                                            int C, int S, int tw) {
  __shared__ u16 tile[32][33];
  const int t = threadIdx.x;
  const int z = blockIdx.z, h = blockIdx.y;
  const int tc = blockIdx.x / tw, twi = blockIdx.x - tc * tw;
  const int c0 = tc * 32, w0 = twi * 32;
  const size_t SS = (size_t)S * S;
  const u16* sp = src + (size_t)z * C * SS;
  u16* dp = dst + (size_t)z * SS * C;
#pragma unroll
  for (int r = 0; r < 4; ++r) {
    int cl = (t >> 5) * 4 + r, wl = t & 31;
    if (w0 + wl < S) tile[cl][wl] = sp[(size_t)(c0 + cl) * SS + h * S + w0 + wl];
  }
  __syncthreads();
#pragma unroll
  for (int r = 0; r < 4; ++r) {
    int wl = (t >> 5) * 4 + r, cl = t & 31;
    if (w0 + wl < S) dp[((size_t)(h * S + w0 + wl)) * C + c0 + cl] = tile[cl][wl];
  }
}

// ---------------------------------------------------------------------------
// bf16 MFMA implicit-GEMM conv, LDS-FREE (round 11). 64x128 tile, 4 waves
// each 32x64. Every MFMA fragment is a contiguous 16B global address (NHWC
// activations, [M][K'] weights), so lane (fr,kc) loads its A/B fragments
// DIRECTLY with global_load_dwordx4: no LDS, no barriers, no staging.
// Rendezvous cost (measured ~600cy/block-iter in the staged design, r8-r10)
// is eliminated; waves are independent, 1-deep register pipeline, compiler
// counts vmcnt. L2 bytes identical to staged version (clean A/B of
// rendezvous-bound vs L2-BW-bound).
// ---------------------------------------------------------------------------
template<int QDIV, int KW, int STR, bool FUSE>
__global__ __launch_bounds__(256)
void k_gemm(const u16* __restrict__ X, const u16* __restrict__ X2,
            const u16* __restrict__ Wt,
            float* __restrict__ part, int C, int l2C, int Hp, int ipad,
            int l2ohow, int l2ow, int K, int Ksp, int M, int N, Epi ep) {
  const int tid = threadIdx.x, lane = tid & 63, wid = tid >> 6;

  // ---- XCD-aware (n,m) remap (kept from r10; harmless) ----
  int ntile, mtile;
  {
    const int NT = gridDim.x, MT = gridDim.y;
    int nm = blockIdx.x + NT * blockIdx.y;
    if ((NT & 7) == 0) {
      int low = nm & 7, r = nm >> 3;
      mtile = r % MT;
      ntile = ((r / MT) << 3) + low;
    } else { ntile = blockIdx.x; mtile = blockIdx.y; }
  }
  const int n0 = ntile * 128, m0 = mtile * 64;
  const int kb = blockIdx.z * Ksp;
  const int mw = (wid >> 1) * 32, nw = (wid & 1) * 64;
  const int fr = lane & 15, kc = lane >> 4;

  // A fragment pointers: rows m0+mw+{0,16}+fr, k offset kb + kc*8.
  const u16* pa0 = Wt + (size_t)(m0 + mw + fr) * K + kb + kc * 8;
  const u16* pa1 = pa0 + (size_t)16 * K;

  // B fragment pointers: pixels n0+nw+nf*16+fr.
  const u16* pb[4];
  int rowB[4], ohsB[4], owsB[4];
  int q = 0, cnt = 0, khs = 0, kws = 0;
#pragma unroll
  for (int nf = 0; nf < 4; ++nf) {
    int n = n0 + nw + nf * 16 + fr;
    int b = n >> l2ohow, p = n & ((1 << l2ohow) - 1);
    int oh = p >> l2ow, ow = p & ((1 << l2ow) - 1);
    if (QDIV == 1) {
      pb[nf] = X + ((size_t)(b * Hp + oh + ipad) * Hp + (ow + ipad)) * C + kb + kc * 8;
    } else if (QDIV == 5) {
      rowB[nf] = n;
    } else {
      rowB[nf] = b * Hp; ohsB[nf] = oh * STR + ipad; owsB[nf] = ow * STR + ipad;
    }
  }
  if (QDIV == 5) {
    q = kb >> l2C;
    int c0 = kb & (C - 1);
    cnt = (C - c0) >> 5;
    const u16* base = (q < 4) ? (X + (((size_t)q << Hp) << l2C)) : X2;
#pragma unroll
    for (int nf = 0; nf < 4; ++nf)
      pb[nf] = base + (((size_t)rowB[nf]) << l2C) + c0 + kc * 8;
  } else if (QDIV != 1) {
    q = kb >> l2C;
    int c0 = kb & (C - 1);
    cnt = (C - c0) >> 5;
    if (QDIV == 4) { khs = q >> 1; kws = q & 1; } else { khs = q / 3; kws = q - khs * 3; }
#pragma unroll
    for (int nf = 0; nf < 4; ++nf)
      pb[nf] = X + ((size_t)(rowB[nf] + ohsB[nf] + khs) * Hp + (owsB[nf] + kws)) * C + c0 + kc * 8;
  }

  f4v acc[2][4];
#pragma unroll
  for (int i = 0; i < 2; ++i)
#pragma unroll
    for (int j = 0; j < 4; ++j) acc[i][j] = (f4v){0.f, 0.f, 0.f, 0.f};

  auto advB = [&]() {
    if (QDIV == 1) {
#pragma unroll
      for (int nf = 0; nf < 4; ++nf) pb[nf] += 32;
    } else if (--cnt == 0) {
      ++q; cnt = C >> 5;
      if (QDIV == 5) {
        const u16* base = (q < 4) ? (X + (((size_t)q << Hp) << l2C)) : X2;
#pragma unroll
        for (int nf = 0; nf < 4; ++nf)
          pb[nf] = base + (((size_t)rowB[nf]) << l2C) + kc * 8;
      } else {
        if (++kws == KW) { kws = 0; ++khs; }
#pragma unroll
        for (int nf = 0; nf < 4; ++nf)
          pb[nf] = X + ((size_t)(rowB[nf] + ohsB[nf] + khs) * Hp + (owsB[nf] + kws)) * C + kc * 8;
      }
    } else {
#pragma unroll
      for (int nf = 0; nf < 4; ++nf) pb[nf] += 32;
    }
  };

  const int nt = Ksp >> 5;
  // 1-deep register pipeline: load frags(t+1) before MFMAs(t); no barriers.
  s8v a0, a1, b0, b1, b2, b3;
  a0 = *(const s8v*)pa0; a1 = *(const s8v*)pa1;
  b0 = *(const s8v*)pb[0]; b1 = *(const s8v*)pb[1];
  b2 = *(const s8v*)pb[2]; b3 = *(const s8v*)pb[3];
  pa0 += 32; pa1 += 32; advB();
  for (int t = 0; t < nt - 1; ++t) {
    s8v c0, c1, d0, d1, d2, d3;
    c0 = *(const s8v*)pa0; c1 = *(const s8v*)pa1;
    d0 = *(const s8v*)pb[0]; d1 = *(const s8v*)pb[1];
    d2 = *(const s8v*)pb[2]; d3 = *(const s8v*)pb[3];
    pa0 += 32; pa1 += 32; advB();
    acc[0][0] = __builtin_amdgcn_mfma_f32_16x16x32_bf16(a0, b0, acc[0][0], 0, 0, 0);
    acc[0][1] = __builtin_amdgcn_mfma_f32_16x16x32_bf16(a0, b1, acc[0][1], 0, 0, 0);
    acc[0][2] = __builtin_amdgcn_mfma_f32_16x16x32_bf16(a0, b2, acc[0][2], 0, 0, 0);
    acc[0][3] = __builtin_amdgcn_mfma_f32_16x16x32_bf16(a0, b3, acc[0][3], 0, 0, 0);
    acc[1][0] = __builtin_amdgcn_mfma_f32_16x16x32_bf16(a1, b0, acc[1][0], 0, 0, 0);
    acc[1][1] = __builtin_amdgcn_mfma_f32_16x16x32_bf16(a1, b1, acc[1][1], 0, 0, 0);
    acc[1][2] = __builtin_amdgcn_mfma_f32_16x16x32_bf16(a1, b2, acc[1][2], 0, 0, 0);
    acc[1][3] = __builtin_amdgcn_mfma_f32_16x16x32_bf16(a1, b3, acc[1][3], 0, 0, 0);
    a0 = c0; a1 = c1; b0 = d0; b1 = d1; b2 = d2; b3 = d3;
  }
  acc[0][0] = __builtin_amdgcn_mfma_f32_16x16x32_bf16(a0, b0, acc[0][0], 0, 0, 0);
  acc[0][1] = __builtin_amdgcn_mfma_f32_16x16x32_bf16(a0, b1, acc[0][1], 0, 0, 0);
  acc[0][2] = __builtin_amdgcn_mfma_f32_16x16x32_bf16(a0, b2, acc[0][2], 0, 0, 0);
  acc[0][3] = __builtin_amdgcn_mfma_f32_16x16x32_bf16(a0, b3, acc[0][3], 0, 0, 0);
  acc[1][0] = __builtin_amdgcn_mfma_f32_16x16x32_bf16(a1, b0, acc[1][0], 0, 0, 0);
  acc[1][1] = __builtin_amdgcn_mfma_f32_16x16x32_bf16(a1, b1, acc[1][1], 0, 0, 0);
  acc[1][2] = __builtin_amdgcn_mfma_f32_16x16x32_bf16(a1, b2, acc[1][2], 0, 0, 0);
  acc[1][3] = __builtin_amdgcn_mfma_f32_16x16x32_bf16(a1, b3, acc[1][3], 0, 0, 0);

  const int r4 = kc * 4;
  if (FUSE) {
    float g = ep.gmode ? *ep.gamma : 0.f;
#pragma unroll
    for (int nf = 0; nf < 4; ++nf) {
      int n = n0 + nw + nf * 16 + fr;
      int b = n >> l2ohow, p = n & ((1 << l2ohow) - 1);
      int oh = p >> l2ow, ow = p & ((1 << l2ow) - 1);
#pragma unroll
      for (int mf = 0; mf < 2; ++mf)
        epi4(acc[mf][nf], m0 + mw + mf * 16 + r4, b, oh, ow, p, M, l2ohow, g, ep);
    }
  } else {
#pragma unroll
    for (int mf = 0; mf < 2; ++mf)
#pragma unroll
      for (int r = 0; r < 4; ++r) {
        int m = m0 + mw + mf * 16 + r4 + r;
        float* pr = part + ((size_t)blockIdx.z * M + m) * N + n0 + nw + fr;
#pragma unroll
        for (int nf = 0; nf < 4; ++nf) pr[nf * 16] = acc[mf][nf][r];
      }
  }
}

// ---------------------------------------------------------------------------
// Split-K reduce + epilogue. part: [z][M][N] fp32, N = 1<<l2N.
// ---------------------------------------------------------------------------
__global__ __launch_bounds__(256) void k_red(const float* __restrict__ part, int z, int M,
                                             int l2N, int l2ohow, int l2ow, Epi ep) {
  size_t MN = ((size_t)M) << l2N;
  int N = 1 << l2N;
  float g = ep.gmode ? *ep.gamma : 0.f;
  for (size_t e = (size_t)blockIdx.x * 256 + threadIdx.x; e < MN; e += (size_t)gridDim.x * 256) {
    float v = 0.f;
    for (int s = 0; s < z; ++s) v += part[(size_t)s * MN + e];
    int m = (int)(e >> l2N), n = (int)(e & (N - 1));
    int b = n >> l2ohow, p = n & ((1 << l2ohow) - 1);
    int oh = p >> l2ow, ow = p & ((1 << l2ow) - 1);
    epi_apply_store(v, m, b, oh, ow, p, M, l2ohow, g, ep);
  }
}

// ---------------------------------------------------------------------------
// ws layout (u16 element offsets). Total 110,100,480 u16 = 220.2 MB.
// ---------------------------------------------------------------------------
static const size_t WR_BA3 = 0, WR_BA4 = 327680, WR_BA5 = 1638400,
  WR_P51 = 6881280, WR_P51D = 7143424, WR_P52 = 7405568, WR_P41 = 7995392,
  WR_P41D = 8126464, WR_P42 = 8257536, WR_P31 = 8847360, WR_P31D = 8912896,
  WR_P32 = 8978432, WR_P6 = 9568256, WR_P7 = 11927552, WR_C34 = 12517376,
  WR_C45 = 13107200, WR_C35 = 13369344;
static const size_t O_C3N = 13631488, O_C4N = 22020096, O_C5N = 26214400,
  O_C3BA = 28311552, O_C4BA = 36700160, O_C5BA = 40894464,
  O_CAT = 42991616, O_SCR = 76546048;
static const size_t O_P3D = O_CAT, O_P3PRE = O_CAT + 8921088,
  O_P4PRE = O_CAT + 17842176, O_P3D1 = O_CAT + 20209664,
  O_P4D = O_CAT + 22306816, O_P4D1 = O_CAT + 24403968,
  O_P3D2 = O_CAT + 24928256, O_P5PRE = O_CAT + 25452544,
  O_P5S = O_CAT + 26116096, O_P6R = O_CAT + 26640384, O_C5P = O_CAT + 26845184;

extern "C" void kernel_launch(void* const* d_in, const int* in_sizes, int n_in,
                              void* d_out, int out_size, void* d_ws, size_t ws_size,
                              hipStream_t stream) {
  (void)in_sizes; (void)n_in; (void)out_size; (void)ws_size;
  const float* C3 = (const float*)d_in[0];
  const float* C4 = (const float*)d_in[1];
  const float* C5 = (const float*)d_in[2];
  const float* ba3_w = (const float*)d_in[3];  const float* ba3_b = (const float*)d_in[4];
  const float* ba4_w = (const float*)d_in[5];  const float* ba4_b = (const float*)d_in[6];
  const float* ba5_w = (const float*)d_in[7];  const float* ba5_b = (const float*)d_in[8];
  const float* p5_1_w = (const float*)d_in[9];  const float* p5_1_b = (const float*)d_in[10];
  const float* p5_1d_w = (const float*)d_in[11]; const float* p5_1d_b = (const float*)d_in[12];
  const float* p5_2_w = (const float*)d_in[13]; const float* p5_2_b = (const float*)d_in[14];
  const float* p4_1_w = (const float*)d_in[15]; const float* p4_1_b = (const float*)d_in[16];
  const float* p4_1d_w = (const float*)d_in[17]; const float* p4_1d_b = (const float*)d_in[18];
  const float* p4_2_w = (const float*)d_in[19]; const float* p4_2_b = (const float*)d_in[20];
  const float* p3_1_w = (const float*)d_in[21]; const float* p3_1_b = (const float*)d_in[22];
  const float* p3_1d_w = (const float*)d_in[23]; const float* p3_1d_b = (const float*)d_in[24];
  const float* p3_2_w = (const float*)d_in[25]; const float* p3_2_b = (const float*)d_in[26];
  const float* p6_w = (const float*)d_in[27]; const float* p6_b = (const float*)d_in[28];
  const float* p7_w = (const float*)d_in[29]; const float* p7_b = (const float*)d_in[30];
  const float* c34_w = (const float*)d_in[31]; const float* c34_b = (const float*)d_in[32];
  const float* c45_w = (const float*)d_in[33]; const float* c45_b = (const float*)d_in[34];
  const float* c35_w = (const float*)d_in[35]; const float* c35_b = (const float*)d_in[36];
  const float* g3 = (const float*)d_in[37];
  const float* g4 = (const float*)d_in[38];
  const float* g5 = (const float*)d_in[39];

  float* out = (float*)d_out;
  float* O3 = out;
  float* O4 = out + 8388608;
  float* O5 = out + 10485760;
  float* P6o = out + 11010048;
  float* P7o = out + 11141120;

  u16* wsu = (u16*)d_ws;
  u16* c3n = wsu + O_C3N;  u16* c4n = wsu + O_C4N;  u16* c5n = wsu + O_C5N;
  u16* c3ba = wsu + O_C3BA; u16* c4ba = wsu + O_C4BA; u16* c5ba = wsu + O_C5BA;
  u16* catb = wsu + O_CAT;
  u16* scr = wsu + O_SCR;
  u16* p3d = wsu + O_P3D;  u16* p3d1 = wsu + O_P3D1; u16* p3d2 = wsu + O_P3D2;
  u16* p4d = wsu + O_P4D;  u16* p4d1 = wsu + O_P4D1;
  u16* p5pre = wsu + O_P5PRE; u16* p5s = wsu + O_P5S; u16* p4pre = wsu + O_P4PRE;
  u16* p3pre = wsu + O_P3PRE; u16* p6r = wsu + O_P6R; u16* c5p = wsu + O_C5P;
  float* part = (float*)scr;
  float* partba = (float*)scr;

  const Epi enone = {nullptr, nullptr,0,0,0, nullptr,0,0,0, nullptr,nullptr,0,0,0, nullptr,0,0,0, nullptr};

  // ---- weight conversion ----
  WTab tab;
  int ti = 0, blk = 0;
  auto add = [&](const float* s, size_t off, int M, int K, int l2Cin, int mode) {
    int kt = (K + 255) / 256;
    tab.s[ti].src = s; tab.s[ti].dst = wsu + off; tab.s[ti].K = K;
    tab.s[ti].l2Cin = l2Cin; tab.s[ti].mode = mode;
    tab.s[ti].ktiles = kt; tab.s[ti].blk0 = blk;
    blk += M * kt; ++ti;
  };
  add(ba3_w, WR_BA3, 256, 1280, 8, 1);
  add(ba4_w, WR_BA4, 512, 2560, 9, 1);
  add(ba5_w, WR_BA5, 1024, 5120, 10, 1);
  add(p5_1_w, WR_P51, 256, 1024, 10, 0);
  add(p5_1d_w, WR_P51D, 256, 1024, 10, 0);
  add(p5_2_w, WR_P52, 256, 2304, 8, 0);
  add(p4_1_w, WR_P41, 256, 512, 9, 0);
  add(p4_1d_w, WR_P41D, 256, 512, 9, 0);
  add(p4_2_w, WR_P42, 256, 2304, 8, 0);
  add(p3_1_w, WR_P31, 256, 256, 8, 0);
  add(p3_1d_w, WR_P31D, 256, 256, 8, 0);
  add(p3_2_w, WR_P32, 256, 2304, 8, 0);
  add(p6_w, WR_P6, 256, 9216, 10, 0);
  add(p7_w, WR_P7, 256, 2304, 8, 0);
  add(c34_w, WR_C34, 256, 2304, 8, 0);
  add(c45_w, WR_C45, 256, 1024, 8, 0);
  add(c35_w, WR_C35, 256, 1024, 8, 0);
  k_cvt_w<<<blk, 256, 0, stream>>>(tab);

  // ---- input NHWC conversions ----
  k_cvt_x<<<dim3(16,64,8), 256, 0, stream>>>(C3, c3n, 256, 64, 64, 64, 0, 2);
  k_cvt_x<<<dim3(16,32,8), 256, 0, stream>>>(C4, c4n, 512, 32, 32, 32, 0, 1);
  k_cvt_x<<<dim3(32,16,8), 256, 0, stream>>>(C5, c5n, 1024, 16, 16, 16, 0, 1);

  // ================= BA phase =================
  k_scan2<64, 6><<<2048, 256, 0, stream>>>(C3, scr, 8);
  k_tr<<<dim3(16,64,32), 256, 0, stream>>>(scr, catb, 256, 64, 2);
  {
    Epi ep = {ba3_b, nullptr,0,0,0, nullptr,0,0,0, nullptr,nullptr,0,0,0, c3ba,64,0,0, nullptr};
    k_gemm<5,1,1,true><<<dim3(256,4,1), 256, 0, stream>>>(
        catb, c3n, wsu + WR_BA3, nullptr, 256, 8, 15, 0, 12, 6, 1280, 1280, 256, 32768, ep);
  }
  k_scan2<32, 5><<<4096, 256, 0, stream>>>(C4, scr, 9);
  k_tr<<<dim3(16,32,32), 256, 0, stream>>>(scr, catb, 512, 32, 1);
  k_gemm<5,1,1,false><<<dim3(64,8,2), 256, 0, stream>>>(
      catb, c4n, wsu + WR_BA4, partba, 512, 9, 13, 0, 10, 5, 2560, 1280, 512, 8192, enone);
  {
    Epi ep = {ba4_b, nullptr,0,0,0, nullptr,0,0,0, nullptr,nullptr,0,0,0, c4ba,32,0,0, nullptr};
    k_red<<<2048, 256, 0, stream>>>(partba, 2, 512, 13, 10, 5, ep);
  }
  k_scan2<16, 4><<<8192, 256, 0, stream>>>(C5, scr, 10);
  k_tr<<<dim3(32,16,32), 256, 0, stream>>>(scr, catb, 1024, 16, 1);
  k_gemm<5,1,1,false><<<dim3(16,16,4), 256, 0, stream>>>(
      catb, c5n, wsu + WR_BA5, partba, 1024, 10, 11, 0, 8, 4, 5120, 1280, 1024, 2048, enone);
  {
    Epi ep = {ba5_b, nullptr,0,0,0, nullptr,0,0,0, nullptr,nullptr,0,0,0, c5ba,16,0,0, nullptr};
    k_red<<<2048, 256, 0, stream>>>(partba, 4, 1024, 11, 8, 4, ep);
  }

  // ---- CAT area free: zero padded persistents, build c5p ----
  hipMemsetAsync(p3d, 0, (size_t)8921088 * 2, stream);
  hipMemsetAsync(p3pre, 0, (size_t)8921088 * 2, stream);
  hipMemsetAsync(p4pre, 0, (size_t)2367488 * 2, stream);
  hipMemsetAsync(p5pre, 0, (size_t)663552 * 2, stream);
  hipMemsetAsync(p6r, 0, (size_t)204800 * 2, stream);
  hipMemsetAsync(c5p, 0, (size_t)2654208 * 2, stream);
  k_cvt_x<<<dim3(32,16,8), 256, 0, stream>>>(C5, c5p, 1024, 16, 16, 18, 1, 1);

  // ================= dual (bottom-up) path =================
  {
    Epi ep = {p3_1d_b, nullptr,0,0,0, nullptr,0,0,0, nullptr,nullptr,0,0,0, p3d,66,1,0, nullptr};
    k_gemm<1,1,1,true><<<dim3(256,4,1), 256, 0, stream>>>(
        c3ba, nullptr, wsu + WR_P31D, nullptr, 256, 0, 64, 0, 12, 6, 256, 256, 256, 32768, ep);
  }
  k_gemm<9,3,2,false><<<dim3(64,4,4), 256, 0, stream>>>(
      p3d, nullptr, wsu + WR_C34, part, 256, 8, 66, 0, 10, 5, 2304, 576, 256, 8192, enone);
  {
    Epi ep = {c34_b, nullptr,0,0,0, nullptr,0,0,0, nullptr,nullptr,0,0,0, p3d1,32,0,0, nullptr};
    k_red<<<2048, 256, 0, stream>>>(part, 4, 256, 13, 10, 5, ep);
  }
  k_gemm<4,2,2,false><<<dim3(16,4,8), 256, 0, stream>>>(
      p3d1, nullptr, wsu + WR_C35, part, 256, 8, 32, 0, 8, 4, 1024, 128, 256, 2048, enone);
  {
    Epi ep = {c35_b, nullptr,0,0,0, nullptr,0,0,0, nullptr,nullptr,0,0,0, p3d2,16,0,0, nullptr};
    k_red<<<2048, 256, 0, stream>>>(part, 8, 256, 11, 8, 4, ep);
  }
  k_gemm<1,1,1,false><<<dim3(64,4,4), 256, 0, stream>>>(
      c4ba, nullptr, wsu + WR_P41D, part, 512, 0, 32, 0, 10, 5, 512, 128, 256, 8192, enone);
  {
    Epi ep = {p4_1d_b, p3d1,32,0,0, nullptr,0,0,0, nullptr,nullptr,0,0,0, p4d,32,0,0, nullptr};
    k_red<<<2048, 256, 0, stream>>>(part, 4, 256, 13, 10, 5, ep);
  }
  k_gemm<4,2,2,false><<<dim3(16,4,8), 256, 0, stream>>>(
      p4d, nullptr, wsu + WR_C45, part, 256, 8, 32, 0, 8, 4, 1024, 128, 256, 2048, enone);
  {
    Epi ep = {c45_b, nullptr,0,0,0, nullptr,0,0,0, nullptr,nullptr,0,0,0, p4d1,16,0,0, nullptr};
    k_red<<<2048, 256, 0, stream>>>(part, 8, 256, 11, 8, 4, ep);
  }

  // ================= top-down path =================
  k_gemm<1,1,1,false><<<dim3(16,4,8), 256, 0, stream>>>(
      c5n, nullptr, wsu + WR_P51, part, 1024, 0, 16, 0, 8, 4, 1024, 128, 256, 2048, enone);
  {
    Epi ep = {p5_1_b, nullptr,0,0,0, nullptr,0,0,0, nullptr,nullptr,0,0,0, p5pre,18,1,0, nullptr};
    k_red<<<2048, 256, 0, stream>>>(part, 8, 256, 11, 8, 4, ep);
  }
  k_gemm<9,3,1,false><<<dim3(16,4,8), 256, 0, stream>>>(
      p5pre, nullptr, wsu + WR_P52, part, 256, 8, 18, 0, 8, 4, 2304, 288, 256, 2048, enone);
  {
    Epi ep = {p5_2_b, nullptr,0,0,0, nullptr,0,0,0, nullptr,nullptr,0,0,0, p5s,16,0,0, nullptr};
    k_red<<<2048, 256, 0, stream>>>(part, 8, 256, 11, 8, 4, ep);
  }
  k_gemm<1,1,1,false><<<dim3(64,4,4), 256, 0, stream>>>(
      c4n, nullptr, wsu + WR_P41, part, 512, 0, 32, 0, 10, 5, 512, 128, 256, 8192, enone);
  {
    Epi ep = {p4_1_b, p5pre,18,1,1, nullptr,0,0,0, nullptr,nullptr,0,0,0, p4pre,34,1,0, nullptr};
    k_red<<<2048, 256, 0, stream>>>(part, 4, 256, 13, 10, 5, ep);
  }
  k_gemm<9,3,1,false><<<dim3(64,4,4), 256, 0, stream>>>(
      p4pre, nullptr, wsu + WR_P42, part, 256, 8, 34, 0, 10, 5, 2304, 576, 256, 8192, enone);
  {
    Epi ep = {p4_2_b, nullptr,0,0,0, nullptr,0,0,0, g4,p4d,32,0,1, nullptr,0,0,0, O4};
    k_red<<<2048, 256, 0, stream>>>(part, 4, 256, 13, 10, 5, ep);
  }
  {
    Epi ep = {p3_1_b, p4pre,34,1,1, p5pre,18,1,2, nullptr,nullptr,0,0,0, p3pre,66,1,0, nullptr};
    k_gemm<1,1,1,true><<<dim3(256,4,1), 256, 0, stream>>>(
        c3n, nullptr, wsu + WR_P31, nullptr, 256, 0, 64, 0, 12, 6, 256, 256, 256, 32768, ep);
  }
  {
    Epi ep = {p3_2_b, nullptr,0,0,0, nullptr,0,0,0, g3,p3d,66,1,1, nullptr,0,0,0, O3};
    k_gemm<9,3,1,true><<<dim3(256,4,1), 256, 0, stream>>>(
        p3pre, nullptr, wsu + WR_P32, nullptr, 256, 8, 66, 0, 12, 6, 2304, 2304, 256, 32768, ep);
  }
  k_gemm<1,1,1,false><<<dim3(16,4,8), 256, 0, stream>>>(
      c5ba, nullptr, wsu + WR_P51D, part, 1024, 0, 16, 0, 8, 4, 1024, 128, 256, 2048, enone);
  {
    Epi ep = {p5_1d_b, p4d1,16,0,0, p3d2,16,0,0, g5,p5s,16,0,2, nullptr,0,0,0, O5};
    k_red<<<2048, 256, 0, stream>>>(part, 8, 256, 11, 8, 4, ep);
  }

  // ================= P6 / P7 =================
  k_gemm<9,3,2,false><<<dim3(4,4,32), 256, 0, stream>>>(
      c5p, nullptr, wsu + WR_P6, part, 1024, 10, 18, 0, 6, 3, 9216, 288, 256, 512, enone);
  {
    Epi ep = {p6_b, nullptr,0,0,0, nullptr,0,0,0, nullptr,nullptr,0,0,0, p6r,10,1,1, P6o};
    k_red<<<512, 256, 0, stream>>>(part, 32, 256, 9, 6, 3, ep);
  }
  k_gemm<9,3,2,false><<<dim3(1,4,8), 256, 0, stream>>>(
      p6r, nullptr, wsu + WR_P7, part, 256, 8, 10, 0, 4, 2, 2304, 288, 256, 128, enone);
  {
    Epi ep = {p7_b, nullptr,0,0,0, nullptr,0,0,0, nullptr,nullptr,0,0,0, nullptr,0,0,0, P7o};
    k_red<<<128, 256, 0, stream>>>(part, 8, 256, 7, 4, 2, ep);
  }
}

// Round 12
// 716.667 us; speedup vs baseline: 1.7661x; 1.7661x over previous
//
#include <hip/hip_runtime.h>

typedef unsigned short u16;
typedef __attribute__((ext_vector_type(8))) short s8v;
typedef __attribute__((ext_vector_type(4))) float f4v;

__device__ __forceinline__ u16 f2bf(float f) {
  unsigned int x = __float_as_uint(f);
  return (u16)((x + 0x7fffu + ((x >> 16) & 1u)) >> 16);
}
__device__ __forceinline__ float bf2f(u16 u) {
  return __uint_as_float(((unsigned int)u) << 16);
}
__device__ __forceinline__ void gload16(const void* g, void* l) {
  __builtin_amdgcn_global_load_lds(
      (const __attribute__((address_space(1))) void*)g,
      (__attribute__((address_space(3))) void*)l, 16, 0, 0);
}

// ---------------------------------------------------------------------------
struct Epi {
  const float* bias;
  const u16* r1; int r1Hp, r1pad, r1sh;   // residual adds (C=256 NHWC)
  const u16* r2; int r2Hp, r2pad, r2sh;
  const float* gamma; const u16* other; int oHp, opad, gmode; // 1: g*o+(1-g)*v ; 2: g*v+(1-g)*o
  u16* outB; int oBHp, oBpad, oBrelu;     // bf16 NHWC out (C=M)
  float* outF;                             // fp32 NCHW out
};

__device__ __forceinline__ size_t nhwc_idx(int b, int h, int w, int Hp, int pad, int Cc, int m) {
  return (((size_t)(b * Hp + h + pad)) * Hp + (w + pad)) * Cc + m;
}

// 4 consecutive m per call; NHWC operands coalesced (ushort4), fp32 NCHW scatter.
__device__ __forceinline__ void epi4(f4v a, int mbase, int b, int oh, int ow,
                                     int p, int M, int l2ohow, float g, const Epi& ep) {
  float v[4];
#pragma unroll
  for (int r = 0; r < 4; ++r) v[r] = a[r];
  if (ep.bias) {
    const float* bp = &ep.bias[mbase];
#pragma unroll
    for (int r = 0; r < 4; ++r) v[r] += bp[r];
  }
  if (ep.r1) {
    const u16* rp = &ep.r1[nhwc_idx(b, oh >> ep.r1sh, ow >> ep.r1sh, ep.r1Hp, ep.r1pad, 256, mbase)];
#pragma unroll
    for (int r = 0; r < 4; ++r) v[r] += bf2f(rp[r]);
  }
  if (ep.r2) {
    const u16* rp = &ep.r2[nhwc_idx(b, oh >> ep.r2sh, ow >> ep.r2sh, ep.r2Hp, ep.r2pad, 256, mbase)];
#pragma unroll
    for (int r = 0; r < 4; ++r) v[r] += bf2f(rp[r]);
  }
  if (ep.gmode) {
    const u16* op = &ep.other[nhwc_idx(b, oh, ow, ep.oHp, ep.opad, 256, mbase)];
#pragma unroll
    for (int r = 0; r < 4; ++r) {
      float o = bf2f(op[r]);
      v[r] = (ep.gmode == 1) ? (g * o + (1.f - g) * v[r]) : (g * v[r] + (1.f - g) * o);
    }
  }
  if (ep.outF) {
    float* fp = &ep.outF[(((size_t)(b * M + mbase)) << l2ohow) + p];
#pragma unroll
    for (int r = 0; r < 4; ++r) fp[(size_t)r << l2ohow] = v[r];
  }
  if (ep.outB) {
    u16* obp = &ep.outB[nhwc_idx(b, oh, ow, ep.oBHp, ep.oBpad, M, mbase)];
    ushort4 pk;
    if (ep.oBrelu) { pk.x = f2bf(fmaxf(v[0], 0.f)); pk.y = f2bf(fmaxf(v[1], 0.f));
                     pk.z = f2bf(fmaxf(v[2], 0.f)); pk.w = f2bf(fmaxf(v[3], 0.f)); }
    else { pk.x = f2bf(v[0]); pk.y = f2bf(v[1]); pk.z = f2bf(v[2]); pk.w = f2bf(v[3]); }
    *(ushort4*)obp = pk;
  }
}

// ---------------------------------------------------------------------------
// Weight convert/reorder, one block per (segment, m, ktile), 1 elem/thread.
// ---------------------------------------------------------------------------
struct WSeg { const float* src; u16* dst; int K, l2Cin, mode, ktiles, blk0; };
struct WTab { WSeg s[17]; };

__global__ __launch_bounds__(256) void k_cvt_w(WTab tab) {
  int bid = blockIdx.x;
  int si = 0;
#pragma unroll
  for (int i = 1; i < 17; ++i) si += (bid >= tab.s[i].blk0) ? 1 : 0;
  WSeg sg = tab.s[si];
  int rel = bid - sg.blk0;
  int m = rel / sg.ktiles;
  int kt = rel - m * sg.ktiles;
  int r = kt * 256 + threadIdx.x;
  if (r >= sg.K) return;
  int Cin = 1 << sg.l2Cin;
  int q = r >> sg.l2Cin, c = r & (Cin - 1);
  int sidx;
  if (sg.mode == 1) {
    int og = (q < 4) ? (q + 1) : 0;
    sidx = m * sg.K + og * Cin + c;
  } else {
    int KHW = sg.K >> sg.l2Cin;
    sidx = (m * Cin + c) * KHW + q;
  }
  sg.dst[(size_t)m * sg.K + r] = f2bf(sg.src[sidx]);
}

// ---------------------------------------------------------------------------
// NCHW fp32 -> NHWC bf16 (optional pad), LDS 32x32 transpose tiles.
// ---------------------------------------------------------------------------
__global__ __launch_bounds__(256) void k_cvt_x(const float* __restrict__ in, u16* __restrict__ out,
                                               int C, int H, int W, int Hp, int P, int tw) {
  __shared__ u16 tile[32][33];
  const int t = threadIdx.x;
  const int b = blockIdx.z, h = blockIdx.y;
  const int tc = blockIdx.x / tw, twi = blockIdx.x - tc * tw;
  const int c0 = tc * 32, w0 = twi * 32;
#pragma unroll
  for (int r = 0; r < 4; ++r) {
    int cl = (t >> 5) * 4 + r, wl = t & 31;
    if (w0 + wl < W) tile[cl][wl] = f2bf(in[(((size_t)b * C + c0 + cl) * H + h) * W + w0 + wl]);
  }
  __syncthreads();
#pragma unroll
  for (int r = 0; r < 4; ++r) {
    int wl = (t >> 5) * 4 + r, cl = t & 31;
    if (w0 + wl < W) out[(((size_t)(b * Hp + h + P)) * Hp + (w0 + wl + P)) * C + c0 + cl] = tile[cl][wl];
  }
}

// ---------------------------------------------------------------------------
// Cummax scans, coalesced NCHW bf16 out[g][b*C+c][S*S].
// ---------------------------------------------------------------------------
template<int S, int L2S>
__global__ __launch_bounds__(256) void k_scan2(const float* __restrict__ x,
                                               u16* __restrict__ out, int l2C) {
  __shared__ u16 pl[S][S + 1], rp[S][S + 1], rs[S][S + 1];
  const int pid = blockIdx.x;
  const size_t SS = (size_t)S * S;
  const size_t GS = ((size_t)8 << l2C) * SS;
  const float* xp = x + (size_t)pid * SS;
  u16* g0 = out + (size_t)pid * SS;
  u16* g1 = g0 + GS;
  u16* g2 = g1 + GS;
  u16* g3 = g2 + GS;
  const int t = threadIdx.x;
  for (int idx = t; idx < S * S; idx += 256)
    pl[idx >> L2S][idx & (S - 1)] = f2bf(xp[idx]);
  __syncthreads();
  if (t < S) {
    float m = -INFINITY;
    for (int h = 0; h < S; ++h) { m = fmaxf(m, bf2f(pl[h][t])); g0[h * S + t] = f2bf(m); }
  } else if (t < 2 * S) {
    int c = t - S;
    float m = -INFINITY;
    for (int h = S - 1; h >= 0; --h) { m = fmaxf(m, bf2f(pl[h][c])); g1[h * S + c] = f2bf(m); }
  } else if (t < 3 * S) {
    int h = t - 2 * S;
    float m = -INFINITY;
    for (int w = 0; w < S; ++w) { m = fmaxf(m, bf2f(pl[h][w])); rp[h][w] = f2bf(m); }
  } else if (t < 4 * S) {
    int h = t - 3 * S;
    float m = -INFINITY;
    for (int w = S - 1; w >= 0; --w) { m = fmaxf(m, bf2f(pl[h][w])); rs[h][w] = f2bf(m); }
  }
  __syncthreads();
  for (int idx = t; idx < S * S; idx += 256) {
    g2[idx] = rp[idx >> L2S][idx & (S - 1)];
    g3[idx] = rs[idx >> L2S][idx & (S - 1)];
  }
}

// ---------------------------------------------------------------------------
// bf16 NCHW -> NHWC transpose. src[z][C][S*S] -> dst[z][S*S][C], z = g*8+b.
// ---------------------------------------------------------------------------
__global__ __launch_bounds__(256) void k_tr(const u16* __restrict__ src, u16* __restrict__ dst,
                                            int C, int S, int tw) {
  __shared__ u16 tile[32][33];
  const int t = threadIdx.x;
  const int z = blockIdx.z, h = blockIdx.y;
  const int tc = blockIdx.x / tw, twi = blockIdx.x - tc * tw;
  const int c0 = tc * 32, w0 = twi * 32;
  const size_t SS = (size_t)S * S;
  const u16* sp = src + (size_t)z * C * SS;
  u16* dp = dst + (size_t)z * SS * C;
#pragma unroll
  for (int r = 0; r < 4; ++r) {
    int cl = (t >> 5) * 4 + r, wl = t & 31;
    if (w0 + wl < S) tile[cl][wl] = sp[(size_t)(c0 + cl) * SS + h * S + w0 + wl];
  }
  __syncthreads();
#pragma unroll
  for (int r = 0; r < 4; ++r) {
    int wl = (t >> 5) * 4 + r, cl = t & 31;
    if (w0 + wl < S) dp[((size_t)(h * S + w0 + wl)) * C + c0 + cl] = tile[cl][wl];
  }
}

// ---------------------------------------------------------------------------
// bf16 MFMA implicit-GEMM conv (r10 engine, proven). 64x128 tile, BK=32,
// 4 waves each 32x64. 2 buffers + 2 barriers/iter, counted vmcnt(3).
// XOR swizzle g(row)=(row>>1)&3. XCD-aware (n,m) remap.
// Round-12 change: non-FUSE partials stored [z][N][M] with one float4 per
// acc fragment (4 consecutive m) -> k_red2 reads/writes fully coalesced.
// ---------------------------------------------------------------------------
template<int QDIV, int KW, int STR, bool FUSE>
__global__ __launch_bounds__(256)
void k_gemm(const u16* __restrict__ X, const u16* __restrict__ X2,
            const u16* __restrict__ Wt,
            float* __restrict__ part, int C, int l2C, int Hp, int ipad,
            int l2ohow, int l2ow, int K, int Ksp, int M, int N, Epi ep) {
  __shared__ u16 Al[4096];   // [2][64 rows][32 ch]
  __shared__ u16 Bl[8192];   // [2][128 rows][32 ch]
  const int tid = threadIdx.x, lane = tid & 63, wid = tid >> 6;

  // ---- XCD-aware (n,m) remap ----
  int ntile, mtile;
  {
    const int NT = gridDim.x, MT = gridDim.y;
    int nm = blockIdx.x + NT * blockIdx.y;
    if ((NT & 7) == 0) {
      int low = nm & 7, r = nm >> 3;
      mtile = r % MT;
      ntile = ((r / MT) << 3) + low;
    } else { ntile = blockIdx.x; mtile = blockIdx.y; }
  }
  const int n0 = ntile * 128, m0 = mtile * 64;
  const int kb = blockIdx.z * Ksp;
  const int mw = (wid >> 1) * 32, nw = (wid & 1) * 64;

  const int srow = lane >> 2;                        // row within 16-row group
  const int schunk = (lane & 3) ^ ((srow >> 1) & 3); // XOR-swizzled source chunk

  // A source: weight row m0 + wid*16 + srow, contiguous in K (1 load/wave).
  const u16* pa0 = Wt + (size_t)(m0 + wid * 16 + srow) * K + kb + schunk * 8;

  // B sources (2 loads/wave)
  const u16* pb0 = nullptr; const u16* pb1 = nullptr;
  int rowB[2], ohsB[2], owsB[2];
  int q = 0, cnt = 0, khs = 0, kws = 0;
#pragma unroll
  for (int j = 0; j < 2; ++j) {
    int n = n0 + wid * 32 + j * 16 + srow;
    int b = n >> l2ohow, p = n & ((1 << l2ohow) - 1);
    int oh = p >> l2ow, ow = p & ((1 << l2ow) - 1);
    if (QDIV == 1) {
      const u16* gg = X + ((size_t)(b * Hp + oh + ipad) * Hp + (ow + ipad)) * C + kb + schunk * 8;
      if (j == 0) pb0 = gg; else pb1 = gg;
    } else if (QDIV == 5) {
      rowB[j] = n;
    } else {
      rowB[j] = b * Hp; ohsB[j] = oh * STR + ipad; owsB[j] = ow * STR + ipad;
    }
  }
  if (QDIV == 5) {
    q = kb >> l2C;
    int c0 = kb & (C - 1);
    cnt = (C - c0) >> 5;
    const u16* base = (q < 4) ? (X + (((size_t)q << Hp) << l2C)) : X2;
    pb0 = base + (((size_t)rowB[0]) << l2C) + c0 + schunk * 8;
    pb1 = base + (((size_t)rowB[1]) << l2C) + c0 + schunk * 8;
  } else if (QDIV != 1) {
    q = kb >> l2C;
    int c0 = kb & (C - 1);
    cnt = (C - c0) >> 5;
    if (QDIV == 4) { khs = q >> 1; kws = q & 1; } else { khs = q / 3; kws = q - khs * 3; }
    pb0 = X + ((size_t)(rowB[0] + ohsB[0] + khs) * Hp + (owsB[0] + kws)) * C + c0 + schunk * 8;
    pb1 = X + ((size_t)(rowB[1] + ohsB[1] + khs) * Hp + (owsB[1] + kws)) * C + c0 + schunk * 8;
  }

  f4v acc[2][4];
#pragma unroll
  for (int i = 0; i < 2; ++i)
#pragma unroll
    for (int j = 0; j < 4; ++j) acc[i][j] = (f4v){0.f, 0.f, 0.f, 0.f};

  const int fr = lane & 15, kc = lane >> 4;
  const int fxor = (kc ^ ((fr >> 1) & 3)) * 8;

  auto advB = [&]() {
    if (QDIV == 1) { pb0 += 32; pb1 += 32; }
    else if (--cnt == 0) {
      ++q; cnt = C >> 5;
      if (QDIV == 5) {
        const u16* base = (q < 4) ? (X + (((size_t)q << Hp) << l2C)) : X2;
        pb0 = base + (((size_t)rowB[0]) << l2C) + schunk * 8;
        pb1 = base + (((size_t)rowB[1]) << l2C) + schunk * 8;
      } else {
        if (++kws == KW) { kws = 0; ++khs; }
        pb0 = X + ((size_t)(rowB[0] + ohsB[0] + khs) * Hp + (owsB[0] + kws)) * C + schunk * 8;
        pb1 = X + ((size_t)(rowB[1] + ohsB[1] + khs) * Hp + (owsB[1] + kws)) * C + schunk * 8;
      }
    } else { pb0 += 32; pb1 += 32; }
  };
  auto stage = [&](int buf) {
    u16* la = Al + buf * 2048 + wid * 512;
    u16* lb = Bl + buf * 4096 + wid * 1024;
    gload16(pa0, la);
    gload16(pb0, lb); gload16(pb1, lb + 512);
    pa0 += 32;
    advB();
  };

  const int nt = Ksp >> 5;
  stage(0);
  for (int t = 0; t < nt; ++t) {
    const int cur = t & 1;
    if (t + 1 < nt) {
      stage(cur ^ 1);
      asm volatile("s_waitcnt vmcnt(3)" ::: "memory");
    } else {
      asm volatile("s_waitcnt vmcnt(0)" ::: "memory");
    }
    __builtin_amdgcn_s_barrier();
    asm volatile("" ::: "memory");
    const u16* ca = Al + cur * 2048;
    const u16* cb = Bl + cur * 4096;
    s8v a[2], bv[4];
#pragma unroll
    for (int mf = 0; mf < 2; ++mf) a[mf] = *(const s8v*)&ca[(mw + mf * 16 + fr) * 32 + fxor];
#pragma unroll
    for (int nf = 0; nf < 4; ++nf) bv[nf] = *(const s8v*)&cb[(nw + nf * 16 + fr) * 32 + fxor];
#pragma unroll
    for (int mf = 0; mf < 2; ++mf)
#pragma unroll
      for (int nf = 0; nf < 4; ++nf)
        acc[mf][nf] = __builtin_amdgcn_mfma_f32_16x16x32_bf16(a[mf], bv[nf], acc[mf][nf], 0, 0, 0);
    __builtin_amdgcn_s_barrier();
    asm volatile("" ::: "memory");
  }

  const int r4 = kc * 4;
  if (FUSE) {
    float g = ep.gmode ? *ep.gamma : 0.f;
#pragma unroll
    for (int nf = 0; nf < 4; ++nf) {
      int n = n0 + nw + nf * 16 + fr;
      int b = n >> l2ohow, p = n & ((1 << l2ohow) - 1);
      int oh = p >> l2ow, ow = p & ((1 << l2ow) - 1);
#pragma unroll
      for (int mf = 0; mf < 2; ++mf)
        epi4(acc[mf][nf], m0 + mw + mf * 16 + r4, b, oh, ow, p, M, l2ohow, g, ep);
    }
  } else {
    // [z][N][M] layout, one float4 (4 consecutive m) per fragment
#pragma unroll
    for (int nf = 0; nf < 4; ++nf) {
      int n = n0 + nw + nf * 16 + fr;
      float* pr = part + ((size_t)blockIdx.z * N + n) * M + m0 + mw + r4;
#pragma unroll
      for (int mf = 0; mf < 2; ++mf)
        *(f4v*)&pr[mf * 16] = acc[mf][nf];
    }
  }
}

// ---------------------------------------------------------------------------
// Split-K reduce + epilogue, m-inner coalesced. part: [z][N][M] fp32.
// Thread handles 4 consecutive m of one pixel: float4 part reads, ushort4
// NHWC accesses via epi4. fp32 NCHW outF stays scattered (small tensors).
// ---------------------------------------------------------------------------
__global__ __launch_bounds__(256)
void k_red2(const float* __restrict__ part, int z, int l2N, int l2M4, int M,
            int l2ohow, int l2ow, Epi ep) {
  const size_t total = (size_t)1 << (l2N + l2M4);
  const int N = 1 << l2N;
  float g = ep.gmode ? *ep.gamma : 0.f;
  for (size_t t = (size_t)blockIdx.x * 256 + threadIdx.x; t < total;
       t += (size_t)gridDim.x * 256) {
    int m4 = (int)(t & ((1u << l2M4) - 1));
    int n = (int)(t >> l2M4);
    int m = m4 << 2;
    f4v v = (f4v){0.f, 0.f, 0.f, 0.f};
    for (int s = 0; s < z; ++s) {
      f4v x = *(const f4v*)&part[((size_t)s * N + n) * M + m];
      v = v + x;
    }
    int b = n >> l2ohow, p = n & ((1 << l2ohow) - 1);
    int oh = p >> l2ow, ow = p & ((1 << l2ow) - 1);
    epi4(v, m, b, oh, ow, p, M, l2ohow, g, ep);
  }
}

// ---------------------------------------------------------------------------
// ws layout (u16 element offsets). Total 110,100,480 u16 = 220.2 MB.
// ---------------------------------------------------------------------------
static const size_t WR_BA3 = 0, WR_BA4 = 327680, WR_BA5 = 1638400,
  WR_P51 = 6881280, WR_P51D = 7143424, WR_P52 = 7405568, WR_P41 = 7995392,
  WR_P41D = 8126464, WR_P42 = 8257536, WR_P31 = 8847360, WR_P31D = 8912896,
  WR_P32 = 8978432, WR_P6 = 9568256, WR_P7 = 11927552, WR_C34 = 12517376,
  WR_C45 = 13107200, WR_C35 = 13369344;
static const size_t O_C3N = 13631488, O_C4N = 22020096, O_C5N = 26214400,
  O_C3BA = 28311552, O_C4BA = 36700160, O_C5BA = 40894464,
  O_CAT = 42991616, O_SCR = 76546048;
static const size_t O_P3D = O_CAT, O_P3PRE = O_CAT + 8921088,
  O_P4PRE = O_CAT + 17842176, O_P3D1 = O_CAT + 20209664,
  O_P4D = O_CAT + 22306816, O_P4D1 = O_CAT + 24403968,
  O_P3D2 = O_CAT + 24928256, O_P5PRE = O_CAT + 25452544,
  O_P5S = O_CAT + 26116096, O_P6R = O_CAT + 26640384, O_C5P = O_CAT + 26845184;

extern "C" void kernel_launch(void* const* d_in, const int* in_sizes, int n_in,
                              void* d_out, int out_size, void* d_ws, size_t ws_size,
                              hipStream_t stream) {
  (void)in_sizes; (void)n_in; (void)out_size; (void)ws_size;
  const float* C3 = (const float*)d_in[0];
  const float* C4 = (const float*)d_in[1];
  const float* C5 = (const float*)d_in[2];
  const float* ba3_w = (const float*)d_in[3];  const float* ba3_b = (const float*)d_in[4];
  const float* ba4_w = (const float*)d_in[5];  const float* ba4_b = (const float*)d_in[6];
  const float* ba5_w = (const float*)d_in[7];  const float* ba5_b = (const float*)d_in[8];
  const float* p5_1_w = (const float*)d_in[9];  const float* p5_1_b = (const float*)d_in[10];
  const float* p5_1d_w = (const float*)d_in[11]; const float* p5_1d_b = (const float*)d_in[12];
  const float* p5_2_w = (const float*)d_in[13]; const float* p5_2_b = (const float*)d_in[14];
  const float* p4_1_w = (const float*)d_in[15]; const float* p4_1_b = (const float*)d_in[16];
  const float* p4_1d_w = (const float*)d_in[17]; const float* p4_1d_b = (const float*)d_in[18];
  const float* p4_2_w = (const float*)d_in[19]; const float* p4_2_b = (const float*)d_in[20];
  const float* p3_1_w = (const float*)d_in[21]; const float* p3_1_b = (const float*)d_in[22];
  const float* p3_1d_w = (const float*)d_in[23]; const float* p3_1d_b = (const float*)d_in[24];
  const float* p3_2_w = (const float*)d_in[25]; const float* p3_2_b = (const float*)d_in[26];
  const float* p6_w = (const float*)d_in[27]; const float* p6_b = (const float*)d_in[28];
  const float* p7_w = (const float*)d_in[29]; const float* p7_b = (const float*)d_in[30];
  const float* c34_w = (const float*)d_in[31]; const float* c34_b = (const float*)d_in[32];
  const float* c45_w = (const float*)d_in[33]; const float* c45_b = (const float*)d_in[34];
  const float* c35_w = (const float*)d_in[35]; const float* c35_b = (const float*)d_in[36];
  const float* g3 = (const float*)d_in[37];
  const float* g4 = (const float*)d_in[38];
  const float* g5 = (const float*)d_in[39];

  float* out = (float*)d_out;
  float* O3 = out;
  float* O4 = out + 8388608;
  float* O5 = out + 10485760;
  float* P6o = out + 11010048;
  float* P7o = out + 11141120;

  u16* wsu = (u16*)d_ws;
  u16* c3n = wsu + O_C3N;  u16* c4n = wsu + O_C4N;  u16* c5n = wsu + O_C5N;
  u16* c3ba = wsu + O_C3BA; u16* c4ba = wsu + O_C4BA; u16* c5ba = wsu + O_C5BA;
  u16* catb = wsu + O_CAT;
  u16* scr = wsu + O_SCR;
  u16* p3d = wsu + O_P3D;  u16* p3d1 = wsu + O_P3D1; u16* p3d2 = wsu + O_P3D2;
  u16* p4d = wsu + O_P4D;  u16* p4d1 = wsu + O_P4D1;
  u16* p5pre = wsu + O_P5PRE; u16* p5s = wsu + O_P5S; u16* p4pre = wsu + O_P4PRE;
  u16* p3pre = wsu + O_P3PRE; u16* p6r = wsu + O_P6R; u16* c5p = wsu + O_C5P;
  float* part = (float*)scr;
  float* partba = (float*)scr;

  const Epi enone = {nullptr, nullptr,0,0,0, nullptr,0,0,0, nullptr,nullptr,0,0,0, nullptr,0,0,0, nullptr};

  // ---- weight conversion ----
  WTab tab;
  int ti = 0, blk = 0;
  auto add = [&](const float* s, size_t off, int M, int K, int l2Cin, int mode) {
    int kt = (K + 255) / 256;
    tab.s[ti].src = s; tab.s[ti].dst = wsu + off; tab.s[ti].K = K;
    tab.s[ti].l2Cin = l2Cin; tab.s[ti].mode = mode;
    tab.s[ti].ktiles = kt; tab.s[ti].blk0 = blk;
    blk += M * kt; ++ti;
  };
  add(ba3_w, WR_BA3, 256, 1280, 8, 1);
  add(ba4_w, WR_BA4, 512, 2560, 9, 1);
  add(ba5_w, WR_BA5, 1024, 5120, 10, 1);
  add(p5_1_w, WR_P51, 256, 1024, 10, 0);
  add(p5_1d_w, WR_P51D, 256, 1024, 10, 0);
  add(p5_2_w, WR_P52, 256, 2304, 8, 0);
  add(p4_1_w, WR_P41, 256, 512, 9, 0);
  add(p4_1d_w, WR_P41D, 256, 512, 9, 0);
  add(p4_2_w, WR_P42, 256, 2304, 8, 0);
  add(p3_1_w, WR_P31, 256, 256, 8, 0);
  add(p3_1d_w, WR_P31D, 256, 256, 8, 0);
  add(p3_2_w, WR_P32, 256, 2304, 8, 0);
  add(p6_w, WR_P6, 256, 9216, 10, 0);
  add(p7_w, WR_P7, 256, 2304, 8, 0);
  add(c34_w, WR_C34, 256, 2304, 8, 0);
  add(c45_w, WR_C45, 256, 1024, 8, 0);
  add(c35_w, WR_C35, 256, 1024, 8, 0);
  k_cvt_w<<<blk, 256, 0, stream>>>(tab);

  // ---- input NHWC conversions ----
  k_cvt_x<<<dim3(16,64,8), 256, 0, stream>>>(C3, c3n, 256, 64, 64, 64, 0, 2);
  k_cvt_x<<<dim3(16,32,8), 256, 0, stream>>>(C4, c4n, 512, 32, 32, 32, 0, 1);
  k_cvt_x<<<dim3(32,16,8), 256, 0, stream>>>(C5, c5n, 1024, 16, 16, 16, 0, 1);

  // ================= BA phase =================
  k_scan2<64, 6><<<2048, 256, 0, stream>>>(C3, scr, 8);
  k_tr<<<dim3(16,64,32), 256, 0, stream>>>(scr, catb, 256, 64, 2);
  {
    Epi ep = {ba3_b, nullptr,0,0,0, nullptr,0,0,0, nullptr,nullptr,0,0,0, c3ba,64,0,0, nullptr};
    k_gemm<5,1,1,true><<<dim3(256,4,1), 256, 0, stream>>>(
        catb, c3n, wsu + WR_BA3, nullptr, 256, 8, 15, 0, 12, 6, 1280, 1280, 256, 32768, ep);
  }
  k_scan2<32, 5><<<4096, 256, 0, stream>>>(C4, scr, 9);
  k_tr<<<dim3(16,32,32), 256, 0, stream>>>(scr, catb, 512, 32, 1);
  k_gemm<5,1,1,false><<<dim3(64,8,2), 256, 0, stream>>>(
      catb, c4n, wsu + WR_BA4, partba, 512, 9, 13, 0, 10, 5, 2560, 1280, 512, 8192, enone);
  {
    Epi ep = {ba4_b, nullptr,0,0,0, nullptr,0,0,0, nullptr,nullptr,0,0,0, c4ba,32,0,0, nullptr};
    k_red2<<<2048, 256, 0, stream>>>(partba, 2, 13, 7, 512, 10, 5, ep);
  }
  k_scan2<16, 4><<<8192, 256, 0, stream>>>(C5, scr, 10);
  k_tr<<<dim3(32,16,32), 256, 0, stream>>>(scr, catb, 1024, 16, 1);
  k_gemm<5,1,1,false><<<dim3(16,16,4), 256, 0, stream>>>(
      catb, c5n, wsu + WR_BA5, partba, 1024, 10, 11, 0, 8, 4, 5120, 1280, 1024, 2048, enone);
  {
    Epi ep = {ba5_b, nullptr,0,0,0, nullptr,0,0,0, nullptr,nullptr,0,0,0, c5ba,16,0,0, nullptr};
    k_red2<<<2048, 256, 0, stream>>>(partba, 4, 11, 8, 1024, 8, 4, ep);
  }

  // ---- CAT area free: zero padded persistents, build c5p ----
  hipMemsetAsync(p3d, 0, (size_t)8921088 * 2, stream);
  hipMemsetAsync(p3pre, 0, (size_t)8921088 * 2, stream);
  hipMemsetAsync(p4pre, 0, (size_t)2367488 * 2, stream);
  hipMemsetAsync(p5pre, 0, (size_t)663552 * 2, stream);
  hipMemsetAsync(p6r, 0, (size_t)204800 * 2, stream);
  hipMemsetAsync(c5p, 0, (size_t)2654208 * 2, stream);
  k_cvt_x<<<dim3(32,16,8), 256, 0, stream>>>(C5, c5p, 1024, 16, 16, 18, 1, 1);

  // ================= dual (bottom-up) path =================
  {
    Epi ep = {p3_1d_b, nullptr,0,0,0, nullptr,0,0,0, nullptr,nullptr,0,0,0, p3d,66,1,0, nullptr};
    k_gemm<1,1,1,true><<<dim3(256,4,1), 256, 0, stream>>>(
        c3ba, nullptr, wsu + WR_P31D, nullptr, 256, 0, 64, 0, 12, 6, 256, 256, 256, 32768, ep);
  }
  k_gemm<9,3,2,false><<<dim3(64,4,4), 256, 0, stream>>>(
      p3d, nullptr, wsu + WR_C34, part, 256, 8, 66, 0, 10, 5, 2304, 576, 256, 8192, enone);
  {
    Epi ep = {c34_b, nullptr,0,0,0, nullptr,0,0,0, nullptr,nullptr,0,0,0, p3d1,32,0,0, nullptr};
    k_red2<<<2048, 256, 0, stream>>>(part, 4, 13, 6, 256, 10, 5, ep);
  }
  k_gemm<4,2,2,false><<<dim3(16,4,8), 256, 0, stream>>>(
      p3d1, nullptr, wsu + WR_C35, part, 256, 8, 32, 0, 8, 4, 1024, 128, 256, 2048, enone);
  {
    Epi ep = {c35_b, nullptr,0,0,0, nullptr,0,0,0, nullptr,nullptr,0,0,0, p3d2,16,0,0, nullptr};
    k_red2<<<2048, 256, 0, stream>>>(part, 8, 11, 6, 256, 8, 4, ep);
  }
  k_gemm<1,1,1,false><<<dim3(64,4,4), 256, 0, stream>>>(
      c4ba, nullptr, wsu + WR_P41D, part, 512, 0, 32, 0, 10, 5, 512, 128, 256, 8192, enone);
  {
    Epi ep = {p4_1d_b, p3d1,32,0,0, nullptr,0,0,0, nullptr,nullptr,0,0,0, p4d,32,0,0, nullptr};
    k_red2<<<2048, 256, 0, stream>>>(part, 4, 13, 6, 256, 10, 5, ep);
  }
  k_gemm<4,2,2,false><<<dim3(16,4,8), 256, 0, stream>>>(
      p4d, nullptr, wsu + WR_C45, part, 256, 8, 32, 0, 8, 4, 1024, 128, 256, 2048, enone);
  {
    Epi ep = {c45_b, nullptr,0,0,0, nullptr,0,0,0, nullptr,nullptr,0,0,0, p4d1,16,0,0, nullptr};
    k_red2<<<2048, 256, 0, stream>>>(part, 8, 11, 6, 256, 8, 4, ep);
  }

  // ================= top-down path =================
  k_gemm<1,1,1,false><<<dim3(16,4,8), 256, 0, stream>>>(
      c5n, nullptr, wsu + WR_P51, part, 1024, 0, 16, 0, 8, 4, 1024, 128, 256, 2048, enone);
  {
    Epi ep = {p5_1_b, nullptr,0,0,0, nullptr,0,0,0, nullptr,nullptr,0,0,0, p5pre,18,1,0, nullptr};
    k_red2<<<2048, 256, 0, stream>>>(part, 8, 11, 6, 256, 8, 4, ep);
  }
  k_gemm<9,3,1,false><<<dim3(16,4,8), 256, 0, stream>>>(
      p5pre, nullptr, wsu + WR_P52, part, 256, 8, 18, 0, 8, 4, 2304, 288, 256, 2048, enone);
  {
    Epi ep = {p5_2_b, nullptr,0,0,0, nullptr,0,0,0, nullptr,nullptr,0,0,0, p5s,16,0,0, nullptr};
    k_red2<<<2048, 256, 0, stream>>>(part, 8, 11, 6, 256, 8, 4, ep);
  }
  k_gemm<1,1,1,false><<<dim3(64,4,4), 256, 0, stream>>>(
      c4n, nullptr, wsu + WR_P41, part, 512, 0, 32, 0, 10, 5, 512, 128, 256, 8192, enone);
  {
    Epi ep = {p4_1_b, p5pre,18,1,1, nullptr,0,0,0, nullptr,nullptr,0,0,0, p4pre,34,1,0, nullptr};
    k_red2<<<2048, 256, 0, stream>>>(part, 4, 13, 6, 256, 10, 5, ep);
  }
  k_gemm<9,3,1,false><<<dim3(64,4,4), 256, 0, stream>>>(
      p4pre, nullptr, wsu + WR_P42, part, 256, 8, 34, 0, 10, 5, 2304, 576, 256, 8192, enone);
  {
    Epi ep = {p4_2_b, nullptr,0,0,0, nullptr,0,0,0, g4,p4d,32,0,1, nullptr,0,0,0, O4};
    k_red2<<<2048, 256, 0, stream>>>(part, 4, 13, 6, 256, 10, 5, ep);
  }
  {
    Epi ep = {p3_1_b, p4pre,34,1,1, p5pre,18,1,2, nullptr,nullptr,0,0,0, p3pre,66,1,0, nullptr};
    k_gemm<1,1,1,true><<<dim3(256,4,1), 256, 0, stream>>>(
        c3n, nullptr, wsu + WR_P31, nullptr, 256, 0, 64, 0, 12, 6, 256, 256, 256, 32768, ep);
  }
  {
    Epi ep = {p3_2_b, nullptr,0,0,0, nullptr,0,0,0, g3,p3d,66,1,1, nullptr,0,0,0, O3};
    k_gemm<9,3,1,true><<<dim3(256,4,1), 256, 0, stream>>>(
        p3pre, nullptr, wsu + WR_P32, nullptr, 256, 8, 66, 0, 12, 6, 2304, 2304, 256, 32768, ep);
  }
  k_gemm<1,1,1,false><<<dim3(16,4,8), 256, 0, stream>>>(
      c5ba, nullptr, wsu + WR_P51D, part, 1024, 0, 16, 0, 8, 4, 1024, 128, 256, 2048, enone);
  {
    Epi ep = {p5_1d_b, p4d1,16,0,0, p3d2,16,0,0, g5,p5s,16,0,2, nullptr,0,0,0, O5};
    k_red2<<<2048, 256, 0, stream>>>(part, 8, 11, 6, 256, 8, 4, ep);
  }

  // ================= P6 / P7 =================
  k_gemm<9,3,2,false><<<dim3(4,4,32), 256, 0, stream>>>(
      c5p, nullptr, wsu + WR_P6, part, 1024, 10, 18, 0, 6, 3, 9216, 288, 256, 512, enone);
  {
    Epi ep = {p6_b, nullptr,0,0,0, nullptr,0,0,0, nullptr,nullptr,0,0,0, p6r,10,1,1, P6o};
    k_red2<<<512, 256, 0, stream>>>(part, 32, 9, 6, 256, 6, 3, ep);
  }
  k_gemm<9,3,2,false><<<dim3(1,4,8), 256, 0, stream>>>(
      p6r, nullptr, wsu + WR_P7, part, 256, 8, 10, 0, 4, 2, 2304, 288, 256, 128, enone);
  {
    Epi ep = {p7_b, nullptr,0,0,0, nullptr,0,0,0, nullptr,nullptr,0,0,0, nullptr,0,0,0, P7o};
    k_red2<<<128, 256, 0, stream>>>(part, 8, 7, 6, 256, 4, 2, ep);
  }
}

// Round 13
// 665.420 us; speedup vs baseline: 1.9021x; 1.0770x over previous
//
#include <hip/hip_runtime.h>

typedef unsigned short u16;
typedef __attribute__((ext_vector_type(8))) short s8v;
typedef __attribute__((ext_vector_type(4))) float f4v;

__device__ __forceinline__ u16 f2bf(float f) {
  unsigned int x = __float_as_uint(f);
  return (u16)((x + 0x7fffu + ((x >> 16) & 1u)) >> 16);
}
__device__ __forceinline__ float bf2f(u16 u) {
  return __uint_as_float(((unsigned int)u) << 16);
}
__device__ __forceinline__ void gload16(const void* g, void* l) {
  __builtin_amdgcn_global_load_lds(
      (const __attribute__((address_space(1))) void*)g,
      (__attribute__((address_space(3))) void*)l, 16, 0, 0);
}

// ---------------------------------------------------------------------------
struct Epi {
  const float* bias;
  const u16* r1; int r1Hp, r1pad, r1sh;   // residual adds (C=256 NHWC)
  const u16* r2; int r2Hp, r2pad, r2sh;
  const float* gamma; const u16* other; int oHp, opad, gmode; // 1: g*o+(1-g)*v ; 2: g*v+(1-g)*o
  u16* outB; int oBHp, oBpad, oBrelu;     // bf16 NHWC out (C=M)
  float* outF;                             // fp32 NCHW out
};

__device__ __forceinline__ size_t nhwc_idx(int b, int h, int w, int Hp, int pad, int Cc, int m) {
  return (((size_t)(b * Hp + h + pad)) * Hp + (w + pad)) * Cc + m;
}

// 4 consecutive m per call; NHWC operands coalesced (ushort4), fp32 NCHW scatter.
__device__ __forceinline__ void epi4(f4v a, int mbase, int b, int oh, int ow,
                                     int p, int M, int l2ohow, float g, const Epi& ep) {
  float v[4];
#pragma unroll
  for (int r = 0; r < 4; ++r) v[r] = a[r];
  if (ep.bias) {
    const float* bp = &ep.bias[mbase];
#pragma unroll
    for (int r = 0; r < 4; ++r) v[r] += bp[r];
  }
  if (ep.r1) {
    const u16* rp = &ep.r1[nhwc_idx(b, oh >> ep.r1sh, ow >> ep.r1sh, ep.r1Hp, ep.r1pad, 256, mbase)];
#pragma unroll
    for (int r = 0; r < 4; ++r) v[r] += bf2f(rp[r]);
  }
  if (ep.r2) {
    const u16* rp = &ep.r2[nhwc_idx(b, oh >> ep.r2sh, ow >> ep.r2sh, ep.r2Hp, ep.r2pad, 256, mbase)];
#pragma unroll
    for (int r = 0; r < 4; ++r) v[r] += bf2f(rp[r]);
  }
  if (ep.gmode) {
    const u16* op = &ep.other[nhwc_idx(b, oh, ow, ep.oHp, ep.opad, 256, mbase)];
#pragma unroll
    for (int r = 0; r < 4; ++r) {
      float o = bf2f(op[r]);
      v[r] = (ep.gmode == 1) ? (g * o + (1.f - g) * v[r]) : (g * v[r] + (1.f - g) * o);
    }
  }
  if (ep.outF) {
    float* fp = &ep.outF[(((size_t)(b * M + mbase)) << l2ohow) + p];
#pragma unroll
    for (int r = 0; r < 4; ++r) fp[(size_t)r << l2ohow] = v[r];
  }
  if (ep.outB) {
    u16* obp = &ep.outB[nhwc_idx(b, oh, ow, ep.oBHp, ep.oBpad, M, mbase)];
    ushort4 pk;
    if (ep.oBrelu) { pk.x = f2bf(fmaxf(v[0], 0.f)); pk.y = f2bf(fmaxf(v[1], 0.f));
                     pk.z = f2bf(fmaxf(v[2], 0.f)); pk.w = f2bf(fmaxf(v[3], 0.f)); }
    else { pk.x = f2bf(v[0]); pk.y = f2bf(v[1]); pk.z = f2bf(v[2]); pk.w = f2bf(v[3]); }
    *(ushort4*)obp = pk;
  }
}

// ---------------------------------------------------------------------------
// Weight convert/reorder, one block per (segment, m, ktile), 1 elem/thread.
// ---------------------------------------------------------------------------
struct WSeg { const float* src; u16* dst; int K, l2Cin, mode, ktiles, blk0; };
struct WTab { WSeg s[17]; };

__global__ __launch_bounds__(256) void k_cvt_w(WTab tab) {
  int bid = blockIdx.x;
  int si = 0;
#pragma unroll
  for (int i = 1; i < 17; ++i) si += (bid >= tab.s[i].blk0) ? 1 : 0;
  WSeg sg = tab.s[si];
  int rel = bid - sg.blk0;
  int m = rel / sg.ktiles;
  int kt = rel - m * sg.ktiles;
  int r = kt * 256 + threadIdx.x;
  if (r >= sg.K) return;
  int Cin = 1 << sg.l2Cin;
  int q = r >> sg.l2Cin, c = r & (Cin - 1);
  int sidx;
  if (sg.mode == 1) {
    int og = (q < 4) ? (q + 1) : 0;
    sidx = m * sg.K + og * Cin + c;
  } else {
    int KHW = sg.K >> sg.l2Cin;
    sidx = (m * Cin + c) * KHW + q;
  }
  sg.dst[(size_t)m * sg.K + r] = f2bf(sg.src[sidx]);
}

// ---------------------------------------------------------------------------
// NCHW fp32 -> NHWC bf16 (optional pad), LDS 32x32 transpose tiles.
// ---------------------------------------------------------------------------
__global__ __launch_bounds__(256) void k_cvt_x(const float* __restrict__ in, u16* __restrict__ out,
                                               int C, int H, int W, int Hp, int P, int tw) {
  __shared__ u16 tile[32][33];
  const int t = threadIdx.x;
  const int b = blockIdx.z, h = blockIdx.y;
  const int tc = blockIdx.x / tw, twi = blockIdx.x - tc * tw;
  const int c0 = tc * 32, w0 = twi * 32;
#pragma unroll
  for (int r = 0; r < 4; ++r) {
    int cl = (t >> 5) * 4 + r, wl = t & 31;
    if (w0 + wl < W) tile[cl][wl] = f2bf(in[(((size_t)b * C + c0 + cl) * H + h) * W + w0 + wl]);
  }
  __syncthreads();
#pragma unroll
  for (int r = 0; r < 4; ++r) {
    int wl = (t >> 5) * 4 + r, cl = t & 31;
    if (w0 + wl < W) out[(((size_t)(b * Hp + h + P)) * Hp + (w0 + wl + P)) * C + c0 + cl] = tile[cl][wl];
  }
}

// ---------------------------------------------------------------------------
// NHWC-direct cummax scans (round 13: replaces k_scan2 + k_tr round trip).
// Input = NHWC bf16 tensor (c3n/c4n/c5n); outputs written directly into the
// NHWC cat group tensors. Fully coalesced: each h/w step reads/writes
// contiguous [.. , c0..C) segments; running max lives in registers.
// blockIdx.y = direction (0 fwd -> out0, 1 bwd -> out1).
// Thread mapping: cpw = C/4 threads per column; 1024/C columns per block.
// ---------------------------------------------------------------------------
__global__ __launch_bounds__(256)
void k_scanH(const u16* __restrict__ in, u16* __restrict__ out0, u16* __restrict__ out1,
             int S, int C) {
  const int cpw = C >> 2;
  const int wpb = 256 / cpw;
  const int strips = S / wpb;
  const int t = threadIdx.x;
  const int wl = t / cpw, c4 = t - wl * cpw;
  const int bb = blockIdx.x / strips, strip = blockIdx.x - bb * strips;
  const int w = strip * wpb + wl;
  const size_t hstr = (size_t)S * C;
  const size_t base = (((size_t)bb * S) * S + w) * C + c4 * 4;
  float m0 = -INFINITY, m1 = -INFINITY, m2 = -INFINITY, m3 = -INFINITY;
  if (blockIdx.y == 0) {
    for (int h = 0; h < S; ++h) {
      ushort4 v = *(const ushort4*)&in[base + (size_t)h * hstr];
      m0 = fmaxf(m0, bf2f(v.x)); m1 = fmaxf(m1, bf2f(v.y));
      m2 = fmaxf(m2, bf2f(v.z)); m3 = fmaxf(m3, bf2f(v.w));
      ushort4 o; o.x = f2bf(m0); o.y = f2bf(m1); o.z = f2bf(m2); o.w = f2bf(m3);
      *(ushort4*)&out0[base + (size_t)h * hstr] = o;
    }
  } else {
    for (int h = S - 1; h >= 0; --h) {
      ushort4 v = *(const ushort4*)&in[base + (size_t)h * hstr];
      m0 = fmaxf(m0, bf2f(v.x)); m1 = fmaxf(m1, bf2f(v.y));
      m2 = fmaxf(m2, bf2f(v.z)); m3 = fmaxf(m3, bf2f(v.w));
      ushort4 o; o.x = f2bf(m0); o.y = f2bf(m1); o.z = f2bf(m2); o.w = f2bf(m3);
      *(ushort4*)&out1[base + (size_t)h * hstr] = o;
    }
  }
}

__global__ __launch_bounds__(256)
void k_scanW(const u16* __restrict__ in, u16* __restrict__ out0, u16* __restrict__ out1,
             int S, int C) {
  const int cph = C >> 2;
  const int hpb = 256 / cph;
  const int strips = S / hpb;
  const int t = threadIdx.x;
  const int hl = t / cph, c4 = t - hl * cph;
  const int bb = blockIdx.x / strips, strip = blockIdx.x - bb * strips;
  const int h = strip * hpb + hl;
  const size_t wstr = (size_t)C;
  const size_t base = (((size_t)bb * S + h) * S) * C + c4 * 4;
  float m0 = -INFINITY, m1 = -INFINITY, m2 = -INFINITY, m3 = -INFINITY;
  if (blockIdx.y == 0) {
    for (int w = 0; w < S; ++w) {
      ushort4 v = *(const ushort4*)&in[base + (size_t)w * wstr];
      m0 = fmaxf(m0, bf2f(v.x)); m1 = fmaxf(m1, bf2f(v.y));
      m2 = fmaxf(m2, bf2f(v.z)); m3 = fmaxf(m3, bf2f(v.w));
      ushort4 o; o.x = f2bf(m0); o.y = f2bf(m1); o.z = f2bf(m2); o.w = f2bf(m3);
      *(ushort4*)&out0[base + (size_t)w * wstr] = o;
    }
  } else {
    for (int w = S - 1; w >= 0; --w) {
      ushort4 v = *(const ushort4*)&in[base + (size_t)w * wstr];
      m0 = fmaxf(m0, bf2f(v.x)); m1 = fmaxf(m1, bf2f(v.y));
      m2 = fmaxf(m2, bf2f(v.z)); m3 = fmaxf(m3, bf2f(v.w));
      ushort4 o; o.x = f2bf(m0); o.y = f2bf(m1); o.z = f2bf(m2); o.w = f2bf(m3);
      *(ushort4*)&out1[base + (size_t)w * wstr] = o;
    }
  }
}

// ---------------------------------------------------------------------------
// bf16 MFMA implicit-GEMM conv (r10 engine, proven). 64x128 tile, BK=32,
// 4 waves each 32x64. 2 buffers + 2 barriers/iter, counted vmcnt(3).
// XOR swizzle g(row)=(row>>1)&3. XCD-aware (n,m) remap.
// Non-FUSE partials stored [z][N][M], one float4 per acc fragment.
// ---------------------------------------------------------------------------
template<int QDIV, int KW, int STR, bool FUSE>
__global__ __launch_bounds__(256)
void k_gemm(const u16* __restrict__ X, const u16* __restrict__ X2,
            const u16* __restrict__ Wt,
            float* __restrict__ part, int C, int l2C, int Hp, int ipad,
            int l2ohow, int l2ow, int K, int Ksp, int M, int N, Epi ep) {
  __shared__ u16 Al[4096];   // [2][64 rows][32 ch]
  __shared__ u16 Bl[8192];   // [2][128 rows][32 ch]
  const int tid = threadIdx.x, lane = tid & 63, wid = tid >> 6;

  // ---- XCD-aware (n,m) remap ----
  int ntile, mtile;
  {
    const int NT = gridDim.x, MT = gridDim.y;
    int nm = blockIdx.x + NT * blockIdx.y;
    if ((NT & 7) == 0) {
      int low = nm & 7, r = nm >> 3;
      mtile = r % MT;
      ntile = ((r / MT) << 3) + low;
    } else { ntile = blockIdx.x; mtile = blockIdx.y; }
  }
  const int n0 = ntile * 128, m0 = mtile * 64;
  const int kb = blockIdx.z * Ksp;
  const int mw = (wid >> 1) * 32, nw = (wid & 1) * 64;

  const int srow = lane >> 2;                        // row within 16-row group
  const int schunk = (lane & 3) ^ ((srow >> 1) & 3); // XOR-swizzled source chunk

  // A source: weight row m0 + wid*16 + srow, contiguous in K (1 load/wave).
  const u16* pa0 = Wt + (size_t)(m0 + wid * 16 + srow) * K + kb + schunk * 8;

  // B sources (2 loads/wave)
  const u16* pb0 = nullptr; const u16* pb1 = nullptr;
  int rowB[2], ohsB[2], owsB[2];
  int q = 0, cnt = 0, khs = 0, kws = 0;
#pragma unroll
  for (int j = 0; j < 2; ++j) {
    int n = n0 + wid * 32 + j * 16 + srow;
    int b = n >> l2ohow, p = n & ((1 << l2ohow) - 1);
    int oh = p >> l2ow, ow = p & ((1 << l2ow) - 1);
    if (QDIV == 1) {
      const u16* gg = X + ((size_t)(b * Hp + oh + ipad) * Hp + (ow + ipad)) * C + kb + schunk * 8;
      if (j == 0) pb0 = gg; else pb1 = gg;
    } else if (QDIV == 5) {
      rowB[j] = n;
    } else {
      rowB[j] = b * Hp; ohsB[j] = oh * STR + ipad; owsB[j] = ow * STR + ipad;
    }
  }
  if (QDIV == 5) {
    q = kb >> l2C;
    int c0 = kb & (C - 1);
    cnt = (C - c0) >> 5;
    const u16* base = (q < 4) ? (X + (((size_t)q << Hp) << l2C)) : X2;
    pb0 = base + (((size_t)rowB[0]) << l2C) + c0 + schunk * 8;
    pb1 = base + (((size_t)rowB[1]) << l2C) + c0 + schunk * 8;
  } else if (QDIV != 1) {
    q = kb >> l2C;
    int c0 = kb & (C - 1);
    cnt = (C - c0) >> 5;
    if (QDIV == 4) { khs = q >> 1; kws = q & 1; } else { khs = q / 3; kws = q - khs * 3; }
    pb0 = X + ((size_t)(rowB[0] + ohsB[0] + khs) * Hp + (owsB[0] + kws)) * C + c0 + schunk * 8;
    pb1 = X + ((size_t)(rowB[1] + ohsB[1] + khs) * Hp + (owsB[1] + kws)) * C + c0 + schunk * 8;
  }

  f4v acc[2][4];
#pragma unroll
  for (int i = 0; i < 2; ++i)
#pragma unroll
    for (int j = 0; j < 4; ++j) acc[i][j] = (f4v){0.f, 0.f, 0.f, 0.f};

  const int fr = lane & 15, kc = lane >> 4;
  const int fxor = (kc ^ ((fr >> 1) & 3)) * 8;

  auto advB = [&]() {
    if (QDIV == 1) { pb0 += 32; pb1 += 32; }
    else if (--cnt == 0) {
      ++q; cnt = C >> 5;
      if (QDIV == 5) {
        const u16* base = (q < 4) ? (X + (((size_t)q << Hp) << l2C)) : X2;
        pb0 = base + (((size_t)rowB[0]) << l2C) + schunk * 8;
        pb1 = base + (((size_t)rowB[1]) << l2C) + schunk * 8;
      } else {
        if (++kws == KW) { kws = 0; ++khs; }
        pb0 = X + ((size_t)(rowB[0] + ohsB[0] + khs) * Hp + (owsB[0] + kws)) * C + schunk * 8;
        pb1 = X + ((size_t)(rowB[1] + ohsB[1] + khs) * Hp + (owsB[1] + kws)) * C + schunk * 8;
      }
    } else { pb0 += 32; pb1 += 32; }
  };
  auto stage = [&](int buf) {
    u16* la = Al + buf * 2048 + wid * 512;
    u16* lb = Bl + buf * 4096 + wid * 1024;
    gload16(pa0, la);
    gload16(pb0, lb); gload16(pb1, lb + 512);
    pa0 += 32;
    advB();
  };

  const int nt = Ksp >> 5;
  stage(0);
  for (int t = 0; t < nt; ++t) {
    const int cur = t & 1;
    if (t + 1 < nt) {
      stage(cur ^ 1);
      asm volatile("s_waitcnt vmcnt(3)" ::: "memory");
    } else {
      asm volatile("s_waitcnt vmcnt(0)" ::: "memory");
    }
    __builtin_amdgcn_s_barrier();
    asm volatile("" ::: "memory");
    const u16* ca = Al + cur * 2048;
    const u16* cb = Bl + cur * 4096;
    s8v a[2], bv[4];
#pragma unroll
    for (int mf = 0; mf < 2; ++mf) a[mf] = *(const s8v*)&ca[(mw + mf * 16 + fr) * 32 + fxor];
#pragma unroll
    for (int nf = 0; nf < 4; ++nf) bv[nf] = *(const s8v*)&cb[(nw + nf * 16 + fr) * 32 + fxor];
#pragma unroll
    for (int mf = 0; mf < 2; ++mf)
#pragma unroll
      for (int nf = 0; nf < 4; ++nf)
        acc[mf][nf] = __builtin_amdgcn_mfma_f32_16x16x32_bf16(a[mf], bv[nf], acc[mf][nf], 0, 0, 0);
    __builtin_amdgcn_s_barrier();
    asm volatile("" ::: "memory");
  }

  const int r4 = kc * 4;
  if (FUSE) {
    float g = ep.gmode ? *ep.gamma : 0.f;
#pragma unroll
    for (int nf = 0; nf < 4; ++nf) {
      int n = n0 + nw + nf * 16 + fr;
      int b = n >> l2ohow, p = n & ((1 << l2ohow) - 1);
      int oh = p >> l2ow, ow = p & ((1 << l2ow) - 1);
#pragma unroll
      for (int mf = 0; mf < 2; ++mf)
        epi4(acc[mf][nf], m0 + mw + mf * 16 + r4, b, oh, ow, p, M, l2ohow, g, ep);
    }
  } else {
    // [z][N][M] layout, one float4 (4 consecutive m) per fragment
#pragma unroll
    for (int nf = 0; nf < 4; ++nf) {
      int n = n0 + nw + nf * 16 + fr;
      float* pr = part + ((size_t)blockIdx.z * N + n) * M + m0 + mw + r4;
#pragma unroll
      for (int mf = 0; mf < 2; ++mf)
        *(f4v*)&pr[mf * 16] = acc[mf][nf];
    }
  }
}

// ---------------------------------------------------------------------------
// Split-K reduce + epilogue, m-inner coalesced. part: [z][N][M] fp32.
// ---------------------------------------------------------------------------
__global__ __launch_bounds__(256)
void k_red2(const float* __restrict__ part, int z, int l2N, int l2M4, int M,
            int l2ohow, int l2ow, Epi ep) {
  const size_t total = (size_t)1 << (l2N + l2M4);
  const int N = 1 << l2N;
  float g = ep.gmode ? *ep.gamma : 0.f;
  for (size_t t = (size_t)blockIdx.x * 256 + threadIdx.x; t < total;
       t += (size_t)gridDim.x * 256) {
    int m4 = (int)(t & ((1u << l2M4) - 1));
    int n = (int)(t >> l2M4);
    int m = m4 << 2;
    f4v v = (f4v){0.f, 0.f, 0.f, 0.f};
    for (int s = 0; s < z; ++s) {
      f4v x = *(const f4v*)&part[((size_t)s * N + n) * M + m];
      v = v + x;
    }
    int b = n >> l2ohow, p = n & ((1 << l2ohow) - 1);
    int oh = p >> l2ow, ow = p & ((1 << l2ow) - 1);
    epi4(v, m, b, oh, ow, p, M, l2ohow, g, ep);
  }
}

// ---------------------------------------------------------------------------
// ws layout (u16 element offsets). Total 110,100,480 u16 = 220.2 MB.
// ---------------------------------------------------------------------------
static const size_t WR_BA3 = 0, WR_BA4 = 327680, WR_BA5 = 1638400,
  WR_P51 = 6881280, WR_P51D = 7143424, WR_P52 = 7405568, WR_P41 = 7995392,
  WR_P41D = 8126464, WR_P42 = 8257536, WR_P31 = 8847360, WR_P31D = 8912896,
  WR_P32 = 8978432, WR_P6 = 9568256, WR_P7 = 11927552, WR_C34 = 12517376,
  WR_C45 = 13107200, WR_C35 = 13369344;
static const size_t O_C3N = 13631488, O_C4N = 22020096, O_C5N = 26214400,
  O_C3BA = 28311552, O_C4BA = 36700160, O_C5BA = 40894464,
  O_CAT = 42991616, O_SCR = 76546048;
static const size_t O_P3D = O_CAT, O_P3PRE = O_CAT + 8921088,
  O_P4PRE = O_CAT + 17842176, O_P3D1 = O_CAT + 20209664,
  O_P4D = O_CAT + 22306816, O_P4D1 = O_CAT + 24403968,
  O_P3D2 = O_CAT + 24928256, O_P5PRE = O_CAT + 25452544,
  O_P5S = O_CAT + 26116096, O_P6R = O_CAT + 26640384, O_C5P = O_CAT + 26845184;

extern "C" void kernel_launch(void* const* d_in, const int* in_sizes, int n_in,
                              void* d_out, int out_size, void* d_ws, size_t ws_size,
                              hipStream_t stream) {
  (void)in_sizes; (void)n_in; (void)out_size; (void)ws_size;
  const float* C3 = (const float*)d_in[0];
  const float* C4 = (const float*)d_in[1];
  const float* C5 = (const float*)d_in[2];
  const float* ba3_w = (const float*)d_in[3];  const float* ba3_b = (const float*)d_in[4];
  const float* ba4_w = (const float*)d_in[5];  const float* ba4_b = (const float*)d_in[6];
  const float* ba5_w = (const float*)d_in[7];  const float* ba5_b = (const float*)d_in[8];
  const float* p5_1_w = (const float*)d_in[9];  const float* p5_1_b = (const float*)d_in[10];
  const float* p5_1d_w = (const float*)d_in[11]; const float* p5_1d_b = (const float*)d_in[12];
  const float* p5_2_w = (const float*)d_in[13]; const float* p5_2_b = (const float*)d_in[14];
  const float* p4_1_w = (const float*)d_in[15]; const float* p4_1_b = (const float*)d_in[16];
  const float* p4_1d_w = (const float*)d_in[17]; const float* p4_1d_b = (const float*)d_in[18];
  const float* p4_2_w = (const float*)d_in[19]; const float* p4_2_b = (const float*)d_in[20];
  const float* p3_1_w = (const float*)d_in[21]; const float* p3_1_b = (const float*)d_in[22];
  const float* p3_1d_w = (const float*)d_in[23]; const float* p3_1d_b = (const float*)d_in[24];
  const float* p3_2_w = (const float*)d_in[25]; const float* p3_2_b = (const float*)d_in[26];
  const float* p6_w = (const float*)d_in[27]; const float* p6_b = (const float*)d_in[28];
  const float* p7_w = (const float*)d_in[29]; const float* p7_b = (const float*)d_in[30];
  const float* c34_w = (const float*)d_in[31]; const float* c34_b = (const float*)d_in[32];
  const float* c45_w = (const float*)d_in[33]; const float* c45_b = (const float*)d_in[34];
  const float* c35_w = (const float*)d_in[35]; const float* c35_b = (const float*)d_in[36];
  const float* g3 = (const float*)d_in[37];
  const float* g4 = (const float*)d_in[38];
  const float* g5 = (const float*)d_in[39];

  float* out = (float*)d_out;
  float* O3 = out;
  float* O4 = out + 8388608;
  float* O5 = out + 10485760;
  float* P6o = out + 11010048;
  float* P7o = out + 11141120;

  u16* wsu = (u16*)d_ws;
  u16* c3n = wsu + O_C3N;  u16* c4n = wsu + O_C4N;  u16* c5n = wsu + O_C5N;
  u16* c3ba = wsu + O_C3BA; u16* c4ba = wsu + O_C4BA; u16* c5ba = wsu + O_C5BA;
  u16* catb = wsu + O_CAT;
  u16* scr = wsu + O_SCR;
  u16* p3d = wsu + O_P3D;  u16* p3d1 = wsu + O_P3D1; u16* p3d2 = wsu + O_P3D2;
  u16* p4d = wsu + O_P4D;  u16* p4d1 = wsu + O_P4D1;
  u16* p5pre = wsu + O_P5PRE; u16* p5s = wsu + O_P5S; u16* p4pre = wsu + O_P4PRE;
  u16* p3pre = wsu + O_P3PRE; u16* p6r = wsu + O_P6R; u16* c5p = wsu + O_C5P;
  float* part = (float*)scr;
  float* partba = (float*)scr;

  const Epi enone = {nullptr, nullptr,0,0,0, nullptr,0,0,0, nullptr,nullptr,0,0,0, nullptr,0,0,0, nullptr};

  // ---- weight conversion ----
  WTab tab;
  int ti = 0, blk = 0;
  auto add = [&](const float* s, size_t off, int M, int K, int l2Cin, int mode) {
    int kt = (K + 255) / 256;
    tab.s[ti].src = s; tab.s[ti].dst = wsu + off; tab.s[ti].K = K;
    tab.s[ti].l2Cin = l2Cin; tab.s[ti].mode = mode;
    tab.s[ti].ktiles = kt; tab.s[ti].blk0 = blk;
    blk += M * kt; ++ti;
  };
  add(ba3_w, WR_BA3, 256, 1280, 8, 1);
  add(ba4_w, WR_BA4, 512, 2560, 9, 1);
  add(ba5_w, WR_BA5, 1024, 5120, 10, 1);
  add(p5_1_w, WR_P51, 256, 1024, 10, 0);
  add(p5_1d_w, WR_P51D, 256, 1024, 10, 0);
  add(p5_2_w, WR_P52, 256, 2304, 8, 0);
  add(p4_1_w, WR_P41, 256, 512, 9, 0);
  add(p4_1d_w, WR_P41D, 256, 512, 9, 0);
  add(p4_2_w, WR_P42, 256, 2304, 8, 0);
  add(p3_1_w, WR_P31, 256, 256, 8, 0);
  add(p3_1d_w, WR_P31D, 256, 256, 8, 0);
  add(p3_2_w, WR_P32, 256, 2304, 8, 0);
  add(p6_w, WR_P6, 256, 9216, 10, 0);
  add(p7_w, WR_P7, 256, 2304, 8, 0);
  add(c34_w, WR_C34, 256, 2304, 8, 0);
  add(c45_w, WR_C45, 256, 1024, 8, 0);
  add(c35_w, WR_C35, 256, 1024, 8, 0);
  k_cvt_w<<<blk, 256, 0, stream>>>(tab);

  // ---- input NHWC conversions ----
  k_cvt_x<<<dim3(16,64,8), 256, 0, stream>>>(C3, c3n, 256, 64, 64, 64, 0, 2);
  k_cvt_x<<<dim3(16,32,8), 256, 0, stream>>>(C4, c4n, 512, 32, 32, 32, 0, 1);
  k_cvt_x<<<dim3(32,16,8), 256, 0, stream>>>(C5, c5n, 1024, 16, 16, 16, 0, 1);

  // ================= BA phase (NHWC-direct scans) =================
  {
    const size_t GS3 = 8388608;  // 8*64*64*256
    k_scanH<<<dim3(128,2), 256, 0, stream>>>(c3n, catb, catb + GS3, 64, 256);
    k_scanW<<<dim3(128,2), 256, 0, stream>>>(c3n, catb + 2*GS3, catb + 3*GS3, 64, 256);
    Epi ep = {ba3_b, nullptr,0,0,0, nullptr,0,0,0, nullptr,nullptr,0,0,0, c3ba,64,0,0, nullptr};
    k_gemm<5,1,1,true><<<dim3(256,4,1), 256, 0, stream>>>(
        catb, c3n, wsu + WR_BA3, nullptr, 256, 8, 15, 0, 12, 6, 1280, 1280, 256, 32768, ep);
  }
  {
    const size_t GS4 = 4194304;  // 8*32*32*512
    k_scanH<<<dim3(128,2), 256, 0, stream>>>(c4n, catb, catb + GS4, 32, 512);
    k_scanW<<<dim3(128,2), 256, 0, stream>>>(c4n, catb + 2*GS4, catb + 3*GS4, 32, 512);
    k_gemm<5,1,1,false><<<dim3(64,8,2), 256, 0, stream>>>(
        catb, c4n, wsu + WR_BA4, partba, 512, 9, 13, 0, 10, 5, 2560, 1280, 512, 8192, enone);
    Epi ep = {ba4_b, nullptr,0,0,0, nullptr,0,0,0, nullptr,nullptr,0,0,0, c4ba,32,0,0, nullptr};
    k_red2<<<2048, 256, 0, stream>>>(partba, 2, 13, 7, 512, 10, 5, ep);
  }
  {
    const size_t GS5 = 2097152;  // 8*16*16*1024
    k_scanH<<<dim3(128,2), 256, 0, stream>>>(c5n, catb, catb + GS5, 16, 1024);
    k_scanW<<<dim3(128,2), 256, 0, stream>>>(c5n, catb + 2*GS5, catb + 3*GS5, 16, 1024);
    k_gemm<5,1,1,false><<<dim3(16,16,4), 256, 0, stream>>>(
        catb, c5n, wsu + WR_BA5, partba, 1024, 10, 11, 0, 8, 4, 5120, 1280, 1024, 2048, enone);
    Epi ep = {ba5_b, nullptr,0,0,0, nullptr,0,0,0, nullptr,nullptr,0,0,0, c5ba,16,0,0, nullptr};
    k_red2<<<2048, 256, 0, stream>>>(partba, 4, 11, 8, 1024, 8, 4, ep);
  }

  // ---- CAT area free: zero padded persistents, build c5p ----
  hipMemsetAsync(p3d, 0, (size_t)8921088 * 2, stream);
  hipMemsetAsync(p3pre, 0, (size_t)8921088 * 2, stream);
  hipMemsetAsync(p4pre, 0, (size_t)2367488 * 2, stream);
  hipMemsetAsync(p5pre, 0, (size_t)663552 * 2, stream);
  hipMemsetAsync(p6r, 0, (size_t)204800 * 2, stream);
  hipMemsetAsync(c5p, 0, (size_t)2654208 * 2, stream);
  k_cvt_x<<<dim3(32,16,8), 256, 0, stream>>>(C5, c5p, 1024, 16, 16, 18, 1, 1);

  // ================= dual (bottom-up) path =================
  {
    Epi ep = {p3_1d_b, nullptr,0,0,0, nullptr,0,0,0, nullptr,nullptr,0,0,0, p3d,66,1,0, nullptr};
    k_gemm<1,1,1,true><<<dim3(256,4,1), 256, 0, stream>>>(
        c3ba, nullptr, wsu + WR_P31D, nullptr, 256, 0, 64, 0, 12, 6, 256, 256, 256, 32768, ep);
  }
  k_gemm<9,3,2,false><<<dim3(64,4,4), 256, 0, stream>>>(
      p3d, nullptr, wsu + WR_C34, part, 256, 8, 66, 0, 10, 5, 2304, 576, 256, 8192, enone);
  {
    Epi ep = {c34_b, nullptr,0,0,0, nullptr,0,0,0, nullptr,nullptr,0,0,0, p3d1,32,0,0, nullptr};
    k_red2<<<2048, 256, 0, stream>>>(part, 4, 13, 6, 256, 10, 5, ep);
  }
  k_gemm<4,2,2,false><<<dim3(16,4,8), 256, 0, stream>>>(
      p3d1, nullptr, wsu + WR_C35, part, 256, 8, 32, 0, 8, 4, 1024, 128, 256, 2048, enone);
  {
    Epi ep = {c35_b, nullptr,0,0,0, nullptr,0,0,0, nullptr,nullptr,0,0,0, p3d2,16,0,0, nullptr};
    k_red2<<<2048, 256, 0, stream>>>(part, 8, 11, 6, 256, 8, 4, ep);
  }
  k_gemm<1,1,1,false><<<dim3(64,4,4), 256, 0, stream>>>(
      c4ba, nullptr, wsu + WR_P41D, part, 512, 0, 32, 0, 10, 5, 512, 128, 256, 8192, enone);
  {
    Epi ep = {p4_1d_b, p3d1,32,0,0, nullptr,0,0,0, nullptr,nullptr,0,0,0, p4d,32,0,0, nullptr};
    k_red2<<<2048, 256, 0, stream>>>(part, 4, 13, 6, 256, 10, 5, ep);
  }
  k_gemm<4,2,2,false><<<dim3(16,4,8), 256, 0, stream>>>(
      p4d, nullptr, wsu + WR_C45, part, 256, 8, 32, 0, 8, 4, 1024, 128, 256, 2048, enone);
  {
    Epi ep = {c45_b, nullptr,0,0,0, nullptr,0,0,0, nullptr,nullptr,0,0,0, p4d1,16,0,0, nullptr};
    k_red2<<<2048, 256, 0, stream>>>(part, 8, 11, 6, 256, 8, 4, ep);
  }

  // ================= top-down path =================
  k_gemm<1,1,1,false><<<dim3(16,4,8), 256, 0, stream>>>(
      c5n, nullptr, wsu + WR_P51, part, 1024, 0, 16, 0, 8, 4, 1024, 128, 256, 2048, enone);
  {
    Epi ep = {p5_1_b, nullptr,0,0,0, nullptr,0,0,0, nullptr,nullptr,0,0,0, p5pre,18,1,0, nullptr};
    k_red2<<<2048, 256, 0, stream>>>(part, 8, 11, 6, 256, 8, 4, ep);
  }
  k_gemm<9,3,1,false><<<dim3(16,4,8), 256, 0, stream>>>(
      p5pre, nullptr, wsu + WR_P52, part, 256, 8, 18, 0, 8, 4, 2304, 288, 256, 2048, enone);
  {
    Epi ep = {p5_2_b, nullptr,0,0,0, nullptr,0,0,0, nullptr,nullptr,0,0,0, p5s,16,0,0, nullptr};
    k_red2<<<2048, 256, 0, stream>>>(part, 8, 11, 6, 256, 8, 4, ep);
  }
  k_gemm<1,1,1,false><<<dim3(64,4,4), 256, 0, stream>>>(
      c4n, nullptr, wsu + WR_P41, part, 512, 0, 32, 0, 10, 5, 512, 128, 256, 8192, enone);
  {
    Epi ep = {p4_1_b, p5pre,18,1,1, nullptr,0,0,0, nullptr,nullptr,0,0,0, p4pre,34,1,0, nullptr};
    k_red2<<<2048, 256, 0, stream>>>(part, 4, 13, 6, 256, 10, 5, ep);
  }
  k_gemm<9,3,1,false><<<dim3(64,4,4), 256, 0, stream>>>(
      p4pre, nullptr, wsu + WR_P42, part, 256, 8, 34, 0, 10, 5, 2304, 576, 256, 8192, enone);
  {
    Epi ep = {p4_2_b, nullptr,0,0,0, nullptr,0,0,0, g4,p4d,32,0,1, nullptr,0,0,0, O4};
    k_red2<<<2048, 256, 0, stream>>>(part, 4, 13, 6, 256, 10, 5, ep);
  }
  {
    Epi ep = {p3_1_b, p4pre,34,1,1, p5pre,18,1,2, nullptr,nullptr,0,0,0, p3pre,66,1,0, nullptr};
    k_gemm<1,1,1,true><<<dim3(256,4,1), 256, 0, stream>>>(
        c3n, nullptr, wsu + WR_P31, nullptr, 256, 0, 64, 0, 12, 6, 256, 256, 256, 32768, ep);
  }
  {
    Epi ep = {p3_2_b, nullptr,0,0,0, nullptr,0,0,0, g3,p3d,66,1,1, nullptr,0,0,0, O3};
    k_gemm<9,3,1,true><<<dim3(256,4,1), 256, 0, stream>>>(
        p3pre, nullptr, wsu + WR_P32, nullptr, 256, 8, 66, 0, 12, 6, 2304, 2304, 256, 32768, ep);
  }
  k_gemm<1,1,1,false><<<dim3(16,4,8), 256, 0, stream>>>(
      c5ba, nullptr, wsu + WR_P51D, part, 1024, 0, 16, 0, 8, 4, 1024, 128, 256, 2048, enone);
  {
    Epi ep = {p5_1d_b, p4d1,16,0,0, p3d2,16,0,0, g5,p5s,16,0,2, nullptr,0,0,0, O5};
    k_red2<<<2048, 256, 0, stream>>>(part, 8, 11, 6, 256, 8, 4, ep);
  }

  // ================= P6 / P7 =================
  k_gemm<9,3,2,false><<<dim3(4,4,32), 256, 0, stream>>>(
      c5p, nullptr, wsu + WR_P6, part, 1024, 10, 18, 0, 6, 3, 9216, 288, 256, 512, enone);
  {
    Epi ep = {p6_b, nullptr,0,0,0, nullptr,0,0,0, nullptr,nullptr,0,0,0, p6r,10,1,1, P6o};
    k_red2<<<512, 256, 0, stream>>>(part, 32, 9, 6, 256, 6, 3, ep);
  }
  k_gemm<9,3,2,false><<<dim3(1,4,8), 256, 0, stream>>>(
      p6r, nullptr, wsu + WR_P7, part, 256, 8, 10, 0, 4, 2, 2304, 288, 256, 128, enone);
  {
    Epi ep = {p7_b, nullptr,0,0,0, nullptr,0,0,0, nullptr,nullptr,0,0,0, nullptr,0,0,0, P7o};
    k_red2<<<128, 256, 0, stream>>>(part, 8, 7, 6, 256, 4, 2, ep);
  }
}

// Round 14
// 658.736 us; speedup vs baseline: 1.9214x; 1.0101x over previous
//
#include <hip/hip_runtime.h>

typedef unsigned short u16;
typedef __attribute__((ext_vector_type(8))) short s8v;
typedef __attribute__((ext_vector_type(4))) float f4v;

__device__ __forceinline__ u16 f2bf(float f) {
  unsigned int x = __float_as_uint(f);
  return (u16)((x + 0x7fffu + ((x >> 16) & 1u)) >> 16);
}
__device__ __forceinline__ float bf2f(u16 u) {
  return __uint_as_float(((unsigned int)u) << 16);
}
__device__ __forceinline__ void gload16(const void* g, void* l) {
  __builtin_amdgcn_global_load_lds(
      (const __attribute__((address_space(1))) void*)g,
      (__attribute__((address_space(3))) void*)l, 16, 0, 0);
}

// ---------------------------------------------------------------------------
struct Epi {
  const float* bias;
  const u16* r1; int r1Hp, r1pad, r1sh;   // residual adds (C=256 NHWC)
  const u16* r2; int r2Hp, r2pad, r2sh;
  const float* gamma; const u16* other; int oHp, opad, gmode; // 1: g*o+(1-g)*v ; 2: g*v+(1-g)*o
  u16* outB; int oBHp, oBpad, oBrelu;     // bf16 NHWC out (C=M)
  float* outF;                             // fp32 NCHW out
};

__device__ __forceinline__ size_t nhwc_idx(int b, int h, int w, int Hp, int pad, int Cc, int m) {
  return (((size_t)(b * Hp + h + pad)) * Hp + (w + pad)) * Cc + m;
}

// value-only epilogue: bias + residuals + gate (4 consecutive m)
__device__ __forceinline__ f4v epi_val(f4v a, int mbase, int b, int oh, int ow,
                                       float g, const Epi& ep) {
  float v[4];
#pragma unroll
  for (int r = 0; r < 4; ++r) v[r] = a[r];
  if (ep.bias) {
    const float* bp = &ep.bias[mbase];
#pragma unroll
    for (int r = 0; r < 4; ++r) v[r] += bp[r];
  }
  if (ep.r1) {
    const u16* rp = &ep.r1[nhwc_idx(b, oh >> ep.r1sh, ow >> ep.r1sh, ep.r1Hp, ep.r1pad, 256, mbase)];
#pragma unroll
    for (int r = 0; r < 4; ++r) v[r] += bf2f(rp[r]);
  }
  if (ep.r2) {
    const u16* rp = &ep.r2[nhwc_idx(b, oh >> ep.r2sh, ow >> ep.r2sh, ep.r2Hp, ep.r2pad, 256, mbase)];
#pragma unroll
    for (int r = 0; r < 4; ++r) v[r] += bf2f(rp[r]);
  }
  if (ep.gmode) {
    const u16* op = &ep.other[nhwc_idx(b, oh, ow, ep.oHp, ep.opad, 256, mbase)];
#pragma unroll
    for (int r = 0; r < 4; ++r) {
      float o = bf2f(op[r]);
      v[r] = (ep.gmode == 1) ? (g * o + (1.f - g) * v[r]) : (g * v[r] + (1.f - g) * o);
    }
  }
  f4v out;
#pragma unroll
  for (int r = 0; r < 4; ++r) out[r] = v[r];
  return out;
}

__device__ __forceinline__ void epi_storeB(f4v v, int mbase, int b, int oh, int ow,
                                           int M, const Epi& ep) {
  u16* obp = &ep.outB[nhwc_idx(b, oh, ow, ep.oBHp, ep.oBpad, M, mbase)];
  ushort4 pk;
  if (ep.oBrelu) { pk.x = f2bf(fmaxf(v[0], 0.f)); pk.y = f2bf(fmaxf(v[1], 0.f));
                   pk.z = f2bf(fmaxf(v[2], 0.f)); pk.w = f2bf(fmaxf(v[3], 0.f)); }
  else { pk.x = f2bf(v[0]); pk.y = f2bf(v[1]); pk.z = f2bf(v[2]); pk.w = f2bf(v[3]); }
  *(ushort4*)obp = pk;
}

// full epilogue for k_red2 (fp32 NCHW scatter acceptable: small tensors)
__device__ __forceinline__ void epi4(f4v a, int mbase, int b, int oh, int ow,
                                     int p, int M, int l2ohow, float g, const Epi& ep) {
  f4v v = epi_val(a, mbase, b, oh, ow, g, ep);
  if (ep.outF) {
    float* fp = &ep.outF[(((size_t)(b * M + mbase)) << l2ohow) + p];
#pragma unroll
    for (int r = 0; r < 4; ++r) fp[(size_t)r << l2ohow] = v[r];
  }
  if (ep.outB) epi_storeB(v, mbase, b, oh, ow, M, ep);
}

// ---------------------------------------------------------------------------
// Weight convert/reorder, one block per (segment, m, ktile), 1 elem/thread.
// ---------------------------------------------------------------------------
struct WSeg { const float* src; u16* dst; int K, l2Cin, mode, ktiles, blk0; };
struct WTab { WSeg s[17]; };

__global__ __launch_bounds__(256) void k_cvt_w(WTab tab) {
  int bid = blockIdx.x;
  int si = 0;
#pragma unroll
  for (int i = 1; i < 17; ++i) si += (bid >= tab.s[i].blk0) ? 1 : 0;
  WSeg sg = tab.s[si];
  int rel = bid - sg.blk0;
  int m = rel / sg.ktiles;
  int kt = rel - m * sg.ktiles;
  int r = kt * 256 + threadIdx.x;
  if (r >= sg.K) return;
  int Cin = 1 << sg.l2Cin;
  int q = r >> sg.l2Cin, c = r & (Cin - 1);
  int sidx;
  if (sg.mode == 1) {
    int og = (q < 4) ? (q + 1) : 0;
    sidx = m * sg.K + og * Cin + c;
  } else {
    int KHW = sg.K >> sg.l2Cin;
    sidx = (m * Cin + c) * KHW + q;
  }
  sg.dst[(size_t)m * sg.K + r] = f2bf(sg.src[sidx]);
}

// ---------------------------------------------------------------------------
// NCHW fp32 -> NHWC bf16 (optional pad), LDS 32x32 transpose tiles.
// ---------------------------------------------------------------------------
__global__ __launch_bounds__(256) void k_cvt_x(const float* __restrict__ in, u16* __restrict__ out,
                                               int C, int H, int W, int Hp, int P, int tw) {
  __shared__ u16 tile[32][33];
  const int t = threadIdx.x;
  const int b = blockIdx.z, h = blockIdx.y;
  const int tc = blockIdx.x / tw, twi = blockIdx.x - tc * tw;
  const int c0 = tc * 32, w0 = twi * 32;
#pragma unroll
  for (int r = 0; r < 4; ++r) {
    int cl = (t >> 5) * 4 + r, wl = t & 31;
    if (w0 + wl < W) tile[cl][wl] = f2bf(in[(((size_t)b * C + c0 + cl) * H + h) * W + w0 + wl]);
  }
  __syncthreads();
#pragma unroll
  for (int r = 0; r < 4; ++r) {
    int wl = (t >> 5) * 4 + r, cl = t & 31;
    if (w0 + wl < W) out[(((size_t)(b * Hp + h + P)) * Hp + (w0 + wl + P)) * C + c0 + cl] = tile[cl][wl];
  }
}

// ---------------------------------------------------------------------------
// NHWC-direct cummax scans (r13). blockIdx.y = direction.
// ---------------------------------------------------------------------------
__global__ __launch_bounds__(256)
void k_scanH(const u16* __restrict__ in, u16* __restrict__ out0, u16* __restrict__ out1,
             int S, int C) {
  const int cpw = C >> 2;
  const int wpb = 256 / cpw;
  const int strips = S / wpb;
  const int t = threadIdx.x;
  const int wl = t / cpw, c4 = t - wl * cpw;
  const int bb = blockIdx.x / strips, strip = blockIdx.x - bb * strips;
  const int w = strip * wpb + wl;
  const size_t hstr = (size_t)S * C;
  const size_t base = (((size_t)bb * S) * S + w) * C + c4 * 4;
  float m0 = -INFINITY, m1 = -INFINITY, m2 = -INFINITY, m3 = -INFINITY;
  if (blockIdx.y == 0) {
    for (int h = 0; h < S; ++h) {
      ushort4 v = *(const ushort4*)&in[base + (size_t)h * hstr];
      m0 = fmaxf(m0, bf2f(v.x)); m1 = fmaxf(m1, bf2f(v.y));
      m2 = fmaxf(m2, bf2f(v.z)); m3 = fmaxf(m3, bf2f(v.w));
      ushort4 o; o.x = f2bf(m0); o.y = f2bf(m1); o.z = f2bf(m2); o.w = f2bf(m3);
      *(ushort4*)&out0[base + (size_t)h * hstr] = o;
    }
  } else {
    for (int h = S - 1; h >= 0; --h) {
      ushort4 v = *(const ushort4*)&in[base + (size_t)h * hstr];
      m0 = fmaxf(m0, bf2f(v.x)); m1 = fmaxf(m1, bf2f(v.y));
      m2 = fmaxf(m2, bf2f(v.z)); m3 = fmaxf(m3, bf2f(v.w));
      ushort4 o; o.x = f2bf(m0); o.y = f2bf(m1); o.z = f2bf(m2); o.w = f2bf(m3);
      *(ushort4*)&out1[base + (size_t)h * hstr] = o;
    }
  }
}

__global__ __launch_bounds__(256)
void k_scanW(const u16* __restrict__ in, u16* __restrict__ out0, u16* __restrict__ out1,
             int S, int C) {
  const int cph = C >> 2;
  const int hpb = 256 / cph;
  const int strips = S / hpb;
  const int t = threadIdx.x;
  const int hl = t / cph, c4 = t - hl * cph;
  const int bb = blockIdx.x / strips, strip = blockIdx.x - bb * strips;
  const int h = strip * hpb + hl;
  const size_t wstr = (size_t)C;
  const size_t base = (((size_t)bb * S + h) * S) * C + c4 * 4;
  float m0 = -INFINITY, m1 = -INFINITY, m2 = -INFINITY, m3 = -INFINITY;
  if (blockIdx.y == 0) {
    for (int w = 0; w < S; ++w) {
      ushort4 v = *(const ushort4*)&in[base + (size_t)w * wstr];
      m0 = fmaxf(m0, bf2f(v.x)); m1 = fmaxf(m1, bf2f(v.y));
      m2 = fmaxf(m2, bf2f(v.z)); m3 = fmaxf(m3, bf2f(v.w));
      ushort4 o; o.x = f2bf(m0); o.y = f2bf(m1); o.z = f2bf(m2); o.w = f2bf(m3);
      *(ushort4*)&out0[base + (size_t)w * wstr] = o;
    }
  } else {
    for (int w = S - 1; w >= 0; --w) {
      ushort4 v = *(const ushort4*)&in[base + (size_t)w * wstr];
      m0 = fmaxf(m0, bf2f(v.x)); m1 = fmaxf(m1, bf2f(v.y));
      m2 = fmaxf(m2, bf2f(v.z)); m3 = fmaxf(m3, bf2f(v.w));
      ushort4 o; o.x = f2bf(m0); o.y = f2bf(m1); o.z = f2bf(m2); o.w = f2bf(m3);
      *(ushort4*)&out1[base + (size_t)w * wstr] = o;
    }
  }
}

// ---------------------------------------------------------------------------
// bf16 MFMA implicit-GEMM conv (r10 engine). 64x128 tile, BK=32, 4 waves.
// Round-14: LDS-transposed C-tile epilogue — after the K-loop, stage the
// 64x128 fp32 tile into LDS [pixel][68] and write out m-inner: each thread
// covers (pixel, 4 consecutive m) so all NHWC reads/stores are 128B-
// contiguous per pixel; split-K partial writes become 256B float4 runs;
// fp32 NCHW output (p3_2->O3) gets a second pass writing 128B runs per m.
// (r13 profile: K=256 FUSE gemms took ~77us == epilogue-scatter-bound.)
// ---------------------------------------------------------------------------
template<int QDIV, int KW, int STR, bool FUSE>
__global__ __launch_bounds__(256)
void k_gemm(const u16* __restrict__ X, const u16* __restrict__ X2,
            const u16* __restrict__ Wt,
            float* __restrict__ part, int C, int l2C, int Hp, int ipad,
            int l2ohow, int l2ow, int K, int Ksp, int M, int N, Epi ep) {
  __shared__ __align__(16) u16 SMEM[17408];   // 34816B: staging 24KB / Cl 34KB
  u16* Al = SMEM;            // [2][64 rows][32 ch]
  u16* Bl = SMEM + 4096;     // [2][128 rows][32 ch]
  float* Cl = (float*)SMEM;  // [128 pixels][68]
  const int tid = threadIdx.x, lane = tid & 63, wid = tid >> 6;

  // ---- XCD-aware (n,m) remap ----
  int ntile, mtile;
  {
    const int NT = gridDim.x, MT = gridDim.y;
    int nm = blockIdx.x + NT * blockIdx.y;
    if ((NT & 7) == 0) {
      int low = nm & 7, r = nm >> 3;
      mtile = r % MT;
      ntile = ((r / MT) << 3) + low;
    } else { ntile = blockIdx.x; mtile = blockIdx.y; }
  }
  const int n0 = ntile * 128, m0 = mtile * 64;
  const int kb = blockIdx.z * Ksp;
  const int mw = (wid >> 1) * 32, nw = (wid & 1) * 64;

  const int srow = lane >> 2;
  const int schunk = (lane & 3) ^ ((srow >> 1) & 3);

  const u16* pa0 = Wt + (size_t)(m0 + wid * 16 + srow) * K + kb + schunk * 8;

  const u16* pb0 = nullptr; const u16* pb1 = nullptr;
  int rowB[2], ohsB[2], owsB[2];
  int q = 0, cnt = 0, khs = 0, kws = 0;
#pragma unroll
  for (int j = 0; j < 2; ++j) {
    int n = n0 + wid * 32 + j * 16 + srow;
    int b = n >> l2ohow, p = n & ((1 << l2ohow) - 1);
    int oh = p >> l2ow, ow = p & ((1 << l2ow) - 1);
    if (QDIV == 1) {
      const u16* gg = X + ((size_t)(b * Hp + oh + ipad) * Hp + (ow + ipad)) * C + kb + schunk * 8;
      if (j == 0) pb0 = gg; else pb1 = gg;
    } else if (QDIV == 5) {
      rowB[j] = n;
    } else {
      rowB[j] = b * Hp; ohsB[j] = oh * STR + ipad; owsB[j] = ow * STR + ipad;
    }
  }
  if (QDIV == 5) {
    q = kb >> l2C;
    int c0 = kb & (C - 1);
    cnt = (C - c0) >> 5;
    const u16* base = (q < 4) ? (X + (((size_t)q << Hp) << l2C)) : X2;
    pb0 = base + (((size_t)rowB[0]) << l2C) + c0 + schunk * 8;
    pb1 = base + (((size_t)rowB[1]) << l2C) + c0 + schunk * 8;
  } else if (QDIV != 1) {
    q = kb >> l2C;
    int c0 = kb & (C - 1);
    cnt = (C - c0) >> 5;
    if (QDIV == 4) { khs = q >> 1; kws = q & 1; } else { khs = q / 3; kws = q - khs * 3; }
    pb0 = X + ((size_t)(rowB[0] + ohsB[0] + khs) * Hp + (owsB[0] + kws)) * C + c0 + schunk * 8;
    pb1 = X + ((size_t)(rowB[1] + ohsB[1] + khs) * Hp + (owsB[1] + kws)) * C + c0 + schunk * 8;
  }

  f4v acc[2][4];
#pragma unroll
  for (int i = 0; i < 2; ++i)
#pragma unroll
    for (int j = 0; j < 4; ++j) acc[i][j] = (f4v){0.f, 0.f, 0.f, 0.f};

  const int fr = lane & 15, kc = lane >> 4;
  const int fxor = (kc ^ ((fr >> 1) & 3)) * 8;

  auto advB = [&]() {
    if (QDIV == 1) { pb0 += 32; pb1 += 32; }
    else if (--cnt == 0) {
      ++q; cnt = C >> 5;
      if (QDIV == 5) {
        const u16* base = (q < 4) ? (X + (((size_t)q << Hp) << l2C)) : X2;
        pb0 = base + (((size_t)rowB[0]) << l2C) + schunk * 8;
        pb1 = base + (((size_t)rowB[1]) << l2C) + schunk * 8;
      } else {
        if (++kws == KW) { kws = 0; ++khs; }
        pb0 = X + ((size_t)(rowB[0] + ohsB[0] + khs) * Hp + (owsB[0] + kws)) * C + schunk * 8;
        pb1 = X + ((size_t)(rowB[1] + ohsB[1] + khs) * Hp + (owsB[1] + kws)) * C + schunk * 8;
      }
    } else { pb0 += 32; pb1 += 32; }
  };
  auto stage = [&](int buf) {
    u16* la = Al + buf * 2048 + wid * 512;
    u16* lb = Bl + buf * 4096 + wid * 1024;
    gload16(pa0, la);
    gload16(pb0, lb); gload16(pb1, lb + 512);
    pa0 += 32;
    advB();
  };

  const int nt = Ksp >> 5;
  stage(0);
  for (int t = 0; t < nt; ++t) {
    const int cur = t & 1;
    if (t + 1 < nt) {
      stage(cur ^ 1);
      asm volatile("s_waitcnt vmcnt(3)" ::: "memory");
    } else {
      asm volatile("s_waitcnt vmcnt(0)" ::: "memory");
    }
    __builtin_amdgcn_s_barrier();
    asm volatile("" ::: "memory");
    const u16* ca = Al + cur * 2048;
    const u16* cb = Bl + cur * 4096;
    s8v a[2], bv[4];
#pragma unroll
    for (int mf = 0; mf < 2; ++mf) a[mf] = *(const s8v*)&ca[(mw + mf * 16 + fr) * 32 + fxor];
#pragma unroll
    for (int nf = 0; nf < 4; ++nf) bv[nf] = *(const s8v*)&cb[(nw + nf * 16 + fr) * 32 + fxor];
#pragma unroll
    for (int mf = 0; mf < 2; ++mf)
#pragma unroll
      for (int nf = 0; nf < 4; ++nf)
        acc[mf][nf] = __builtin_amdgcn_mfma_f32_16x16x32_bf16(a[mf], bv[nf], acc[mf][nf], 0, 0, 0);
    __builtin_amdgcn_s_barrier();
    asm volatile("" ::: "memory");
  }

  // ---- stage C-tile to LDS: Cl[pixel][68] ----
  const int r4 = kc * 4;
#pragma unroll
  for (int nf = 0; nf < 4; ++nf) {
    int pl = nw + nf * 16 + fr;
#pragma unroll
    for (int mf = 0; mf < 2; ++mf)
      *(f4v*)&Cl[pl * 68 + mw + mf * 16 + r4] = acc[mf][nf];
  }
  __builtin_amdgcn_s_barrier();
  asm volatile("" ::: "memory");

  // ---- m-inner write-out: thread = (pixel prow, 4 consecutive m) ----
  const int ml2 = (tid & 15) << 2;
  const int prow = tid >> 4;
  if (FUSE) {
    float g = ep.gmode ? *ep.gamma : 0.f;
#pragma unroll
    for (int pass = 0; pass < 8; ++pass) {
      int pl = pass * 16 + prow;
      f4v v = *(const f4v*)&Cl[pl * 68 + ml2];
      int n = n0 + pl;
      int b = n >> l2ohow, p = n & ((1 << l2ohow) - 1);
      int oh = p >> l2ow, ow = p & ((1 << l2ow) - 1);
      v = epi_val(v, m0 + ml2, b, oh, ow, g, ep);
      if (ep.outB) epi_storeB(v, m0 + ml2, b, oh, ow, M, ep);
      if (ep.outF) *(f4v*)&Cl[pl * 68 + ml2] = v;   // stash for NCHW pass
    }
    if (ep.outF) {
      __builtin_amdgcn_s_barrier();
      asm volatile("" ::: "memory");
      // NCHW-coalesced pass: thread = (m = tid&63, 32-pixel segment)
      int m = tid & 63, seg = tid >> 6;
      int b0 = n0 >> l2ohow, p0 = n0 & ((1 << l2ohow) - 1);
      float* dst = &ep.outF[(((size_t)(b0 * M + m0 + m)) << l2ohow) + p0 + seg * 32];
#pragma unroll
      for (int i = 0; i < 32; i += 4) {
        int pl = seg * 32 + i;
        float4 o;
        o.x = Cl[(pl + 0) * 68 + m]; o.y = Cl[(pl + 1) * 68 + m];
        o.z = Cl[(pl + 2) * 68 + m]; o.w = Cl[(pl + 3) * 68 + m];
        *(float4*)&dst[i] = o;
      }
    }
  } else {
#pragma unroll
    for (int pass = 0; pass < 8; ++pass) {
      int pl = pass * 16 + prow;
      int n = n0 + pl;
      *(f4v*)&part[((size_t)blockIdx.z * N + n) * M + m0 + ml2] =
          *(const f4v*)&Cl[pl * 68 + ml2];
    }
  }
}

// ---------------------------------------------------------------------------
// Split-K reduce + epilogue, m-inner coalesced. part: [z][N][M] fp32.
// ---------------------------------------------------------------------------
__global__ __launch_bounds__(256)
void k_red2(const float* __restrict__ part, int z, int l2N, int l2M4, int M,
            int l2ohow, int l2ow, Epi ep) {
  const size_t total = (size_t)1 << (l2N + l2M4);
  const int N = 1 << l2N;
  float g = ep.gmode ? *ep.gamma : 0.f;
  for (size_t t = (size_t)blockIdx.x * 256 + threadIdx.x; t < total;
       t += (size_t)gridDim.x * 256) {
    int m4 = (int)(t & ((1u << l2M4) - 1));
    int n = (int)(t >> l2M4);
    int m = m4 << 2;
    f4v v = (f4v){0.f, 0.f, 0.f, 0.f};
    for (int s = 0; s < z; ++s) {
      f4v x = *(const f4v*)&part[((size_t)s * N + n) * M + m];
      v = v + x;
    }
    int b = n >> l2ohow, p = n & ((1 << l2ohow) - 1);
    int oh = p >> l2ow, ow = p & ((1 << l2ow) - 1);
    epi4(v, m, b, oh, ow, p, M, l2ohow, g, ep);
  }
}

// ---------------------------------------------------------------------------
// ws layout (u16 element offsets). Total 110,100,480 u16 = 220.2 MB.
// ---------------------------------------------------------------------------
static const size_t WR_BA3 = 0, WR_BA4 = 327680, WR_BA5 = 1638400,
  WR_P51 = 6881280, WR_P51D = 7143424, WR_P52 = 7405568, WR_P41 = 7995392,
  WR_P41D = 8126464, WR_P42 = 8257536, WR_P31 = 8847360, WR_P31D = 8912896,
  WR_P32 = 8978432, WR_P6 = 9568256, WR_P7 = 11927552, WR_C34 = 12517376,
  WR_C45 = 13107200, WR_C35 = 13369344;
static const size_t O_C3N = 13631488, O_C4N = 22020096, O_C5N = 26214400,
  O_C3BA = 28311552, O_C4BA = 36700160, O_C5BA = 40894464,
  O_CAT = 42991616, O_SCR = 76546048;
static const size_t O_P3D = O_CAT, O_P3PRE = O_CAT + 8921088,
  O_P4PRE = O_CAT + 17842176, O_P3D1 = O_CAT + 20209664,
  O_P4D = O_CAT + 22306816, O_P4D1 = O_CAT + 24403968,
  O_P3D2 = O_CAT + 24928256, O_P5PRE = O_CAT + 25452544,
  O_P5S = O_CAT + 26116096, O_P6R = O_CAT + 26640384, O_C5P = O_CAT + 26845184;

extern "C" void kernel_launch(void* const* d_in, const int* in_sizes, int n_in,
                              void* d_out, int out_size, void* d_ws, size_t ws_size,
                              hipStream_t stream) {
  (void)in_sizes; (void)n_in; (void)out_size; (void)ws_size;
  const float* C3 = (const float*)d_in[0];
  const float* C4 = (const float*)d_in[1];
  const float* C5 = (const float*)d_in[2];
  const float* ba3_w = (const float*)d_in[3];  const float* ba3_b = (const float*)d_in[4];
  const float* ba4_w = (const float*)d_in[5];  const float* ba4_b = (const float*)d_in[6];
  const float* ba5_w = (const float*)d_in[7];  const float* ba5_b = (const float*)d_in[8];
  const float* p5_1_w = (const float*)d_in[9];  const float* p5_1_b = (const float*)d_in[10];
  const float* p5_1d_w = (const float*)d_in[11]; const float* p5_1d_b = (const float*)d_in[12];
  const float* p5_2_w = (const float*)d_in[13]; const float* p5_2_b = (const float*)d_in[14];
  const float* p4_1_w = (const float*)d_in[15]; const float* p4_1_b = (const float*)d_in[16];
  const float* p4_1d_w = (const float*)d_in[17]; const float* p4_1d_b = (const float*)d_in[18];
  const float* p4_2_w = (const float*)d_in[19]; const float* p4_2_b = (const float*)d_in[20];
  const float* p3_1_w = (const float*)d_in[21]; const float* p3_1_b = (const float*)d_in[22];
  const float* p3_1d_w = (const float*)d_in[23]; const float* p3_1d_b = (const float*)d_in[24];
  const float* p3_2_w = (const float*)d_in[25]; const float* p3_2_b = (const float*)d_in[26];
  const float* p6_w = (const float*)d_in[27]; const float* p6_b = (const float*)d_in[28];
  const float* p7_w = (const float*)d_in[29]; const float* p7_b = (const float*)d_in[30];
  const float* c34_w = (const float*)d_in[31]; const float* c34_b = (const float*)d_in[32];
  const float* c45_w = (const float*)d_in[33]; const float* c45_b = (const float*)d_in[34];
  const float* c35_w = (const float*)d_in[35]; const float* c35_b = (const float*)d_in[36];
  const float* g3 = (const float*)d_in[37];
  const float* g4 = (const float*)d_in[38];
  const float* g5 = (const float*)d_in[39];

  float* out = (float*)d_out;
  float* O3 = out;
  float* O4 = out + 8388608;
  float* O5 = out + 10485760;
  float* P6o = out + 11010048;
  float* P7o = out + 11141120;

  u16* wsu = (u16*)d_ws;
  u16* c3n = wsu + O_C3N;  u16* c4n = wsu + O_C4N;  u16* c5n = wsu + O_C5N;
  u16* c3ba = wsu + O_C3BA; u16* c4ba = wsu + O_C4BA; u16* c5ba = wsu + O_C5BA;
  u16* catb = wsu + O_CAT;
  u16* scr = wsu + O_SCR;
  u16* p3d = wsu + O_P3D;  u16* p3d1 = wsu + O_P3D1; u16* p3d2 = wsu + O_P3D2;
  u16* p4d = wsu + O_P4D;  u16* p4d1 = wsu + O_P4D1;
  u16* p5pre = wsu + O_P5PRE; u16* p5s = wsu + O_P5S; u16* p4pre = wsu + O_P4PRE;
  u16* p3pre = wsu + O_P3PRE; u16* p6r = wsu + O_P6R; u16* c5p = wsu + O_C5P;
  float* part = (float*)scr;
  float* partba = (float*)scr;

  const Epi enone = {nullptr, nullptr,0,0,0, nullptr,0,0,0, nullptr,nullptr,0,0,0, nullptr,0,0,0, nullptr};

  // ---- weight conversion ----
  WTab tab;
  int ti = 0, blk = 0;
  auto add = [&](const float* s, size_t off, int M, int K, int l2Cin, int mode) {
    int kt = (K + 255) / 256;
    tab.s[ti].src = s; tab.s[ti].dst = wsu + off; tab.s[ti].K = K;
    tab.s[ti].l2Cin = l2Cin; tab.s[ti].mode = mode;
    tab.s[ti].ktiles = kt; tab.s[ti].blk0 = blk;
    blk += M * kt; ++ti;
  };
  add(ba3_w, WR_BA3, 256, 1280, 8, 1);
  add(ba4_w, WR_BA4, 512, 2560, 9, 1);
  add(ba5_w, WR_BA5, 1024, 5120, 10, 1);
  add(p5_1_w, WR_P51, 256, 1024, 10, 0);
  add(p5_1d_w, WR_P51D, 256, 1024, 10, 0);
  add(p5_2_w, WR_P52, 256, 2304, 8, 0);
  add(p4_1_w, WR_P41, 256, 512, 9, 0);
  add(p4_1d_w, WR_P41D, 256, 512, 9, 0);
  add(p4_2_w, WR_P42, 256, 2304, 8, 0);
  add(p3_1_w, WR_P31, 256, 256, 8, 0);
  add(p3_1d_w, WR_P31D, 256, 256, 8, 0);
  add(p3_2_w, WR_P32, 256, 2304, 8, 0);
  add(p6_w, WR_P6, 256, 9216, 10, 0);
  add(p7_w, WR_P7, 256, 2304, 8, 0);
  add(c34_w, WR_C34, 256, 2304, 8, 0);
  add(c45_w, WR_C45, 256, 1024, 8, 0);
  add(c35_w, WR_C35, 256, 1024, 8, 0);
  k_cvt_w<<<blk, 256, 0, stream>>>(tab);

  // ---- input NHWC conversions ----
  k_cvt_x<<<dim3(16,64,8), 256, 0, stream>>>(C3, c3n, 256, 64, 64, 64, 0, 2);
  k_cvt_x<<<dim3(16,32,8), 256, 0, stream>>>(C4, c4n, 512, 32, 32, 32, 0, 1);
  k_cvt_x<<<dim3(32,16,8), 256, 0, stream>>>(C5, c5n, 1024, 16, 16, 16, 0, 1);

  // ================= BA phase (NHWC-direct scans) =================
  {
    const size_t GS3 = 8388608;
    k_scanH<<<dim3(128,2), 256, 0, stream>>>(c3n, catb, catb + GS3, 64, 256);
    k_scanW<<<dim3(128,2), 256, 0, stream>>>(c3n, catb + 2*GS3, catb + 3*GS3, 64, 256);
    Epi ep = {ba3_b, nullptr,0,0,0, nullptr,0,0,0, nullptr,nullptr,0,0,0, c3ba,64,0,0, nullptr};
    k_gemm<5,1,1,true><<<dim3(256,4,1), 256, 0, stream>>>(
        catb, c3n, wsu + WR_BA3, nullptr, 256, 8, 15, 0, 12, 6, 1280, 1280, 256, 32768, ep);
  }
  {
    const size_t GS4 = 4194304;
    k_scanH<<<dim3(128,2), 256, 0, stream>>>(c4n, catb, catb + GS4, 32, 512);
    k_scanW<<<dim3(128,2), 256, 0, stream>>>(c4n, catb + 2*GS4, catb + 3*GS4, 32, 512);
    k_gemm<5,1,1,false><<<dim3(64,8,2), 256, 0, stream>>>(
        catb, c4n, wsu + WR_BA4, partba, 512, 9, 13, 0, 10, 5, 2560, 1280, 512, 8192, enone);
    Epi ep = {ba4_b, nullptr,0,0,0, nullptr,0,0,0, nullptr,nullptr,0,0,0, c4ba,32,0,0, nullptr};
    k_red2<<<2048, 256, 0, stream>>>(partba, 2, 13, 7, 512, 10, 5, ep);
  }
  {
    const size_t GS5 = 2097152;
    k_scanH<<<dim3(128,2), 256, 0, stream>>>(c5n, catb, catb + GS5, 16, 1024);
    k_scanW<<<dim3(128,2), 256, 0, stream>>>(c5n, catb + 2*GS5, catb + 3*GS5, 16, 1024);
    k_gemm<5,1,1,false><<<dim3(16,16,4), 256, 0, stream>>>(
        catb, c5n, wsu + WR_BA5, partba, 1024, 10, 11, 0, 8, 4, 5120, 1280, 1024, 2048, enone);
    Epi ep = {ba5_b, nullptr,0,0,0, nullptr,0,0,0, nullptr,nullptr,0,0,0, c5ba,16,0,0, nullptr};
    k_red2<<<2048, 256, 0, stream>>>(partba, 4, 11, 8, 1024, 8, 4, ep);
  }

  // ---- CAT area free: zero padded persistents, build c5p ----
  hipMemsetAsync(p3d, 0, (size_t)8921088 * 2, stream);
  hipMemsetAsync(p3pre, 0, (size_t)8921088 * 2, stream);
  hipMemsetAsync(p4pre, 0, (size_t)2367488 * 2, stream);
  hipMemsetAsync(p5pre, 0, (size_t)663552 * 2, stream);
  hipMemsetAsync(p6r, 0, (size_t)204800 * 2, stream);
  hipMemsetAsync(c5p, 0, (size_t)2654208 * 2, stream);
  k_cvt_x<<<dim3(32,16,8), 256, 0, stream>>>(C5, c5p, 1024, 16, 16, 18, 1, 1);

  // ================= dual (bottom-up) path =================
  {
    Epi ep = {p3_1d_b, nullptr,0,0,0, nullptr,0,0,0, nullptr,nullptr,0,0,0, p3d,66,1,0, nullptr};
    k_gemm<1,1,1,true><<<dim3(256,4,1), 256, 0, stream>>>(
        c3ba, nullptr, wsu + WR_P31D, nullptr, 256, 0, 64, 0, 12, 6, 256, 256, 256, 32768, ep);
  }
  k_gemm<9,3,2,false><<<dim3(64,4,4), 256, 0, stream>>>(
      p3d, nullptr, wsu + WR_C34, part, 256, 8, 66, 0, 10, 5, 2304, 576, 256, 8192, enone);
  {
    Epi ep = {c34_b, nullptr,0,0,0, nullptr,0,0,0, nullptr,nullptr,0,0,0, p3d1,32,0,0, nullptr};
    k_red2<<<2048, 256, 0, stream>>>(part, 4, 13, 6, 256, 10, 5, ep);
  }
  k_gemm<4,2,2,false><<<dim3(16,4,8), 256, 0, stream>>>(
      p3d1, nullptr, wsu + WR_C35, part, 256, 8, 32, 0, 8, 4, 1024, 128, 256, 2048, enone);
  {
    Epi ep = {c35_b, nullptr,0,0,0, nullptr,0,0,0, nullptr,nullptr,0,0,0, p3d2,16,0,0, nullptr};
    k_red2<<<2048, 256, 0, stream>>>(part, 8, 11, 6, 256, 8, 4, ep);
  }
  k_gemm<1,1,1,false><<<dim3(64,4,4), 256, 0, stream>>>(
      c4ba, nullptr, wsu + WR_P41D, part, 512, 0, 32, 0, 10, 5, 512, 128, 256, 8192, enone);
  {
    Epi ep = {p4_1d_b, p3d1,32,0,0, nullptr,0,0,0, nullptr,nullptr,0,0,0, p4d,32,0,0, nullptr};
    k_red2<<<2048, 256, 0, stream>>>(part, 4, 13, 6, 256, 10, 5, ep);
  }
  k_gemm<4,2,2,false><<<dim3(16,4,8), 256, 0, stream>>>(
      p4d, nullptr, wsu + WR_C45, part, 256, 8, 32, 0, 8, 4, 1024, 128, 256, 2048, enone);
  {
    Epi ep = {c45_b, nullptr,0,0,0, nullptr,0,0,0, nullptr,nullptr,0,0,0, p4d1,16,0,0, nullptr};
    k_red2<<<2048, 256, 0, stream>>>(part, 8, 11, 6, 256, 8, 4, ep);
  }

  // ================= top-down path =================
  k_gemm<1,1,1,false><<<dim3(16,4,8), 256, 0, stream>>>(
      c5n, nullptr, wsu + WR_P51, part, 1024, 0, 16, 0, 8, 4, 1024, 128, 256, 2048, enone);
  {
    Epi ep = {p5_1_b, nullptr,0,0,0, nullptr,0,0,0, nullptr,nullptr,0,0,0, p5pre,18,1,0, nullptr};
    k_red2<<<2048, 256, 0, stream>>>(part, 8, 11, 6, 256, 8, 4, ep);
  }
  k_gemm<9,3,1,false><<<dim3(16,4,8), 256, 0, stream>>>(
      p5pre, nullptr, wsu + WR_P52, part, 256, 8, 18, 0, 8, 4, 2304, 288, 256, 2048, enone);
  {
    Epi ep = {p5_2_b, nullptr,0,0,0, nullptr,0,0,0, nullptr,nullptr,0,0,0, p5s,16,0,0, nullptr};
    k_red2<<<2048, 256, 0, stream>>>(part, 8, 11, 6, 256, 8, 4, ep);
  }
  k_gemm<1,1,1,false><<<dim3(64,4,4), 256, 0, stream>>>(
      c4n, nullptr, wsu + WR_P41, part, 512, 0, 32, 0, 10, 5, 512, 128, 256, 8192, enone);
  {
    Epi ep = {p4_1_b, p5pre,18,1,1, nullptr,0,0,0, nullptr,nullptr,0,0,0, p4pre,34,1,0, nullptr};
    k_red2<<<2048, 256, 0, stream>>>(part, 4, 13, 6, 256, 10, 5, ep);
  }
  k_gemm<9,3,1,false><<<dim3(64,4,4), 256, 0, stream>>>(
      p4pre, nullptr, wsu + WR_P42, part, 256, 8, 34, 0, 10, 5, 2304, 576, 256, 8192, enone);
  {
    Epi ep = {p4_2_b, nullptr,0,0,0, nullptr,0,0,0, g4,p4d,32,0,1, nullptr,0,0,0, O4};
    k_red2<<<2048, 256, 0, stream>>>(part, 4, 13, 6, 256, 10, 5, ep);
  }
  {
    Epi ep = {p3_1_b, p4pre,34,1,1, p5pre,18,1,2, nullptr,nullptr,0,0,0, p3pre,66,1,0, nullptr};
    k_gemm<1,1,1,true><<<dim3(256,4,1), 256, 0, stream>>>(
        c3n, nullptr, wsu + WR_P31, nullptr, 256, 0, 64, 0, 12, 6, 256, 256, 256, 32768, ep);
  }
  {
    Epi ep = {p3_2_b, nullptr,0,0,0, nullptr,0,0,0, g3,p3d,66,1,1, nullptr,0,0,0, O3};
    k_gemm<9,3,1,true><<<dim3(256,4,1), 256, 0, stream>>>(
        p3pre, nullptr, wsu + WR_P32, nullptr, 256, 8, 66, 0, 12, 6, 2304, 2304, 256, 32768, ep);
  }
  k_gemm<1,1,1,false><<<dim3(16,4,8), 256, 0, stream>>>(
      c5ba, nullptr, wsu + WR_P51D, part, 1024, 0, 16, 0, 8, 4, 1024, 128, 256, 2048, enone);
  {
    Epi ep = {p5_1d_b, p4d1,16,0,0, p3d2,16,0,0, g5,p5s,16,0,2, nullptr,0,0,0, O5};
    k_red2<<<2048, 256, 0, stream>>>(part, 8, 11, 6, 256, 8, 4, ep);
  }

  // ================= P6 / P7 =================
  k_gemm<9,3,2,false><<<dim3(4,4,32), 256, 0, stream>>>(
      c5p, nullptr, wsu + WR_P6, part, 1024, 10, 18, 0, 6, 3, 9216, 288, 256, 512, enone);
  {
    Epi ep = {p6_b, nullptr,0,0,0, nullptr,0,0,0, nullptr,nullptr,0,0,0, p6r,10,1,1, P6o};
    k_red2<<<512, 256, 0, stream>>>(part, 32, 9, 6, 256, 6, 3, ep);
  }
  k_gemm<9,3,2,false><<<dim3(1,4,8), 256, 0, stream>>>(
      p6r, nullptr, wsu + WR_P7, part, 256, 8, 10, 0, 4, 2, 2304, 288, 256, 128, enone);
  {
    Epi ep = {p7_b, nullptr,0,0,0, nullptr,0,0,0, nullptr,nullptr,0,0,0, nullptr,0,0,0, P7o};
    k_red2<<<128, 256, 0, stream>>>(part, 8, 7, 6, 256, 4, 2, ep);
  }
}

// Round 15
// 654.582 us; speedup vs baseline: 1.9336x; 1.0063x over previous
//
#include <hip/hip_runtime.h>

typedef unsigned short u16;
typedef __attribute__((ext_vector_type(8))) short s8v;
typedef __attribute__((ext_vector_type(4))) float f4v;

__device__ __forceinline__ u16 f2bf(float f) {
  unsigned int x = __float_as_uint(f);
  return (u16)((x + 0x7fffu + ((x >> 16) & 1u)) >> 16);
}
__device__ __forceinline__ float bf2f(u16 u) {
  return __uint_as_float(((unsigned int)u) << 16);
}
__device__ __forceinline__ void gload16(const void* g, void* l) {
  __builtin_amdgcn_global_load_lds(
      (const __attribute__((address_space(1))) void*)g,
      (__attribute__((address_space(3))) void*)l, 16, 0, 0);
}

// ---------------------------------------------------------------------------
struct Epi {
  const float* bias;
  const u16* r1; int r1Hp, r1pad, r1sh;   // residual adds (C=256 NHWC)
  const u16* r2; int r2Hp, r2pad, r2sh;
  const float* gamma; const u16* other; int oHp, opad, gmode; // 1: g*o+(1-g)*v ; 2: g*v+(1-g)*o
  u16* outB; int oBHp, oBpad, oBrelu;     // bf16 NHWC out (C=M)
  float* outF;                             // fp32 NCHW out
};

__device__ __forceinline__ size_t nhwc_idx(int b, int h, int w, int Hp, int pad, int Cc, int m) {
  return (((size_t)(b * Hp + h + pad)) * Hp + (w + pad)) * Cc + m;
}

// value-only epilogue: bias + residuals + gate (4 consecutive m)
__device__ __forceinline__ f4v epi_val(f4v a, int mbase, int b, int oh, int ow,
                                       float g, const Epi& ep) {
  float v[4];
#pragma unroll
  for (int r = 0; r < 4; ++r) v[r] = a[r];
  if (ep.bias) {
    const float* bp = &ep.bias[mbase];
#pragma unroll
    for (int r = 0; r < 4; ++r) v[r] += bp[r];
  }
  if (ep.r1) {
    const u16* rp = &ep.r1[nhwc_idx(b, oh >> ep.r1sh, ow >> ep.r1sh, ep.r1Hp, ep.r1pad, 256, mbase)];
#pragma unroll
    for (int r = 0; r < 4; ++r) v[r] += bf2f(rp[r]);
  }
  if (ep.r2) {
    const u16* rp = &ep.r2[nhwc_idx(b, oh >> ep.r2sh, ow >> ep.r2sh, ep.r2Hp, ep.r2pad, 256, mbase)];
#pragma unroll
    for (int r = 0; r < 4; ++r) v[r] += bf2f(rp[r]);
  }
  if (ep.gmode) {
    const u16* op = &ep.other[nhwc_idx(b, oh, ow, ep.oHp, ep.opad, 256, mbase)];
#pragma unroll
    for (int r = 0; r < 4; ++r) {
      float o = bf2f(op[r]);
      v[r] = (ep.gmode == 1) ? (g * o + (1.f - g) * v[r]) : (g * v[r] + (1.f - g) * o);
    }
  }
  f4v out;
#pragma unroll
  for (int r = 0; r < 4; ++r) out[r] = v[r];
  return out;
}

__device__ __forceinline__ void epi_storeB(f4v v, int mbase, int b, int oh, int ow,
                                           int M, const Epi& ep) {
  u16* obp = &ep.outB[nhwc_idx(b, oh, ow, ep.oBHp, ep.oBpad, M, mbase)];
  ushort4 pk;
  if (ep.oBrelu) { pk.x = f2bf(fmaxf(v[0], 0.f)); pk.y = f2bf(fmaxf(v[1], 0.f));
                   pk.z = f2bf(fmaxf(v[2], 0.f)); pk.w = f2bf(fmaxf(v[3], 0.f)); }
  else { pk.x = f2bf(v[0]); pk.y = f2bf(v[1]); pk.z = f2bf(v[2]); pk.w = f2bf(v[3]); }
  *(ushort4*)obp = pk;
}

// full epilogue (4 consecutive m); fp32 NCHW scatter acceptable (small tensors)
__device__ __forceinline__ void epi4(f4v a, int mbase, int b, int oh, int ow,
                                     int p, int M, int l2ohow, float g, const Epi& ep) {
  f4v v = epi_val(a, mbase, b, oh, ow, g, ep);
  if (ep.outF) {
    float* fp = &ep.outF[(((size_t)(b * M + mbase)) << l2ohow) + p];
#pragma unroll
    for (int r = 0; r < 4; ++r) fp[(size_t)r << l2ohow] = v[r];
  }
  if (ep.outB) epi_storeB(v, mbase, b, oh, ow, M, ep);
}

// ---------------------------------------------------------------------------
// Weight convert/reorder, one block per (segment, m, ktile), 1 elem/thread.
// ---------------------------------------------------------------------------
struct WSeg { const float* src; u16* dst; int K, l2Cin, mode, ktiles, blk0; };
struct WTab { WSeg s[17]; };

__global__ __launch_bounds__(256) void k_cvt_w(WTab tab) {
  int bid = blockIdx.x;
  int si = 0;
#pragma unroll
  for (int i = 1; i < 17; ++i) si += (bid >= tab.s[i].blk0) ? 1 : 0;
  WSeg sg = tab.s[si];
  int rel = bid - sg.blk0;
  int m = rel / sg.ktiles;
  int kt = rel - m * sg.ktiles;
  int r = kt * 256 + threadIdx.x;
  if (r >= sg.K) return;
  int Cin = 1 << sg.l2Cin;
  int q = r >> sg.l2Cin, c = r & (Cin - 1);
  int sidx;
  if (sg.mode == 1) {
    int og = (q < 4) ? (q + 1) : 0;
    sidx = m * sg.K + og * Cin + c;
  } else {
    int KHW = sg.K >> sg.l2Cin;
    sidx = (m * Cin + c) * KHW + q;
  }
  sg.dst[(size_t)m * sg.K + r] = f2bf(sg.src[sidx]);
}

// ---------------------------------------------------------------------------
// NCHW fp32 -> NHWC bf16 (optional pad), LDS 32x32 transpose tiles.
// ---------------------------------------------------------------------------
__global__ __launch_bounds__(256) void k_cvt_x(const float* __restrict__ in, u16* __restrict__ out,
                                               int C, int H, int W, int Hp, int P, int tw) {
  __shared__ u16 tile[32][33];
  const int t = threadIdx.x;
  const int b = blockIdx.z, h = blockIdx.y;
  const int tc = blockIdx.x / tw, twi = blockIdx.x - tc * tw;
  const int c0 = tc * 32, w0 = twi * 32;
#pragma unroll
  for (int r = 0; r < 4; ++r) {
    int cl = (t >> 5) * 4 + r, wl = t & 31;
    if (w0 + wl < W) tile[cl][wl] = f2bf(in[(((size_t)b * C + c0 + cl) * H + h) * W + w0 + wl]);
  }
  __syncthreads();
#pragma unroll
  for (int r = 0; r < 4; ++r) {
    int wl = (t >> 5) * 4 + r, cl = t & 31;
    if (w0 + wl < W) out[(((size_t)(b * Hp + h + P)) * Hp + (w0 + wl + P)) * C + c0 + cl] = tile[cl][wl];
  }
}

// ---------------------------------------------------------------------------
// NHWC-direct cummax scans (r13). blockIdx.y = direction.
// ---------------------------------------------------------------------------
__global__ __launch_bounds__(256)
void k_scanH(const u16* __restrict__ in, u16* __restrict__ out0, u16* __restrict__ out1,
             int S, int C) {
  const int cpw = C >> 2;
  const int wpb = 256 / cpw;
  const int strips = S / wpb;
  const int t = threadIdx.x;
  const int wl = t / cpw, c4 = t - wl * cpw;
  const int bb = blockIdx.x / strips, strip = blockIdx.x - bb * strips;
  const int w = strip * wpb + wl;
  const size_t hstr = (size_t)S * C;
  const size_t base = (((size_t)bb * S) * S + w) * C + c4 * 4;
  float m0 = -INFINITY, m1 = -INFINITY, m2 = -INFINITY, m3 = -INFINITY;
  if (blockIdx.y == 0) {
    for (int h = 0; h < S; ++h) {
      ushort4 v = *(const ushort4*)&in[base + (size_t)h * hstr];
      m0 = fmaxf(m0, bf2f(v.x)); m1 = fmaxf(m1, bf2f(v.y));
      m2 = fmaxf(m2, bf2f(v.z)); m3 = fmaxf(m3, bf2f(v.w));
      ushort4 o; o.x = f2bf(m0); o.y = f2bf(m1); o.z = f2bf(m2); o.w = f2bf(m3);
      *(ushort4*)&out0[base + (size_t)h * hstr] = o;
    }
  } else {
    for (int h = S - 1; h >= 0; --h) {
      ushort4 v = *(const ushort4*)&in[base + (size_t)h * hstr];
      m0 = fmaxf(m0, bf2f(v.x)); m1 = fmaxf(m1, bf2f(v.y));
      m2 = fmaxf(m2, bf2f(v.z)); m3 = fmaxf(m3, bf2f(v.w));
      ushort4 o; o.x = f2bf(m0); o.y = f2bf(m1); o.z = f2bf(m2); o.w = f2bf(m3);
      *(ushort4*)&out1[base + (size_t)h * hstr] = o;
    }
  }
}

__global__ __launch_bounds__(256)
void k_scanW(const u16* __restrict__ in, u16* __restrict__ out0, u16* __restrict__ out1,
             int S, int C) {
  const int cph = C >> 2;
  const int hpb = 256 / cph;
  const int strips = S / hpb;
  const int t = threadIdx.x;
  const int hl = t / cph, c4 = t - hl * cph;
  const int bb = blockIdx.x / strips, strip = blockIdx.x - bb * strips;
  const int h = strip * hpb + hl;
  const size_t wstr = (size_t)C;
  const size_t base = (((size_t)bb * S + h) * S) * C + c4 * 4;
  float m0 = -INFINITY, m1 = -INFINITY, m2 = -INFINITY, m3 = -INFINITY;
  if (blockIdx.y == 0) {
    for (int w = 0; w < S; ++w) {
      ushort4 v = *(const ushort4*)&in[base + (size_t)w * wstr];
      m0 = fmaxf(m0, bf2f(v.x)); m1 = fmaxf(m1, bf2f(v.y));
      m2 = fmaxf(m2, bf2f(v.z)); m3 = fmaxf(m3, bf2f(v.w));
      ushort4 o; o.x = f2bf(m0); o.y = f2bf(m1); o.z = f2bf(m2); o.w = f2bf(m3);
      *(ushort4*)&out0[base + (size_t)w * wstr] = o;
    }
  } else {
    for (int w = S - 1; w >= 0; --w) {
      ushort4 v = *(const ushort4*)&in[base + (size_t)w * wstr];
      m0 = fmaxf(m0, bf2f(v.x)); m1 = fmaxf(m1, bf2f(v.y));
      m2 = fmaxf(m2, bf2f(v.z)); m3 = fmaxf(m3, bf2f(v.w));
      ushort4 o; o.x = f2bf(m0); o.y = f2bf(m1); o.z = f2bf(m2); o.w = f2bf(m3);
      *(ushort4*)&out1[base + (size_t)w * wstr] = o;
    }
  }
}

// ---------------------------------------------------------------------------
// bf16 MFMA implicit-GEMM conv (r10 engine). 64x128 tile, BK=32, 4 waves.
// Round-15: FUSE epilogue reverted to direct per-fragment stores (r13 was
// 77us vs r14's LDS version at 86us on the big gemms); non-FUSE keeps the
// r14 LDS-transposed [z][N][M] float4 write-out (that part helped).
// Shared mem sized per-template: FUSE 24KB, non-FUSE 34KB.
// ---------------------------------------------------------------------------
template<int QDIV, int KW, int STR, bool FUSE>
__global__ __launch_bounds__(256)
void k_gemm(const u16* __restrict__ X, const u16* __restrict__ X2,
            const u16* __restrict__ Wt,
            float* __restrict__ part, int C, int l2C, int Hp, int ipad,
            int l2ohow, int l2ow, int K, int Ksp, int M, int N, Epi ep) {
  __shared__ __align__(16) u16 SMEM[FUSE ? 12288 : 17408];
  u16* Al = SMEM;            // [2][64 rows][32 ch]
  u16* Bl = SMEM + 4096;     // [2][128 rows][32 ch]
  float* Cl = (float*)SMEM;  // [128 pixels][68]  (non-FUSE only)
  const int tid = threadIdx.x, lane = tid & 63, wid = tid >> 6;

  // ---- XCD-aware (n,m) remap ----
  int ntile, mtile;
  {
    const int NT = gridDim.x, MT = gridDim.y;
    int nm = blockIdx.x + NT * blockIdx.y;
    if ((NT & 7) == 0) {
      int low = nm & 7, r = nm >> 3;
      mtile = r % MT;
      ntile = ((r / MT) << 3) + low;
    } else { ntile = blockIdx.x; mtile = blockIdx.y; }
  }
  const int n0 = ntile * 128, m0 = mtile * 64;
  const int kb = blockIdx.z * Ksp;
  const int mw = (wid >> 1) * 32, nw = (wid & 1) * 64;

  const int srow = lane >> 2;
  const int schunk = (lane & 3) ^ ((srow >> 1) & 3);

  const u16* pa0 = Wt + (size_t)(m0 + wid * 16 + srow) * K + kb + schunk * 8;

  const u16* pb0 = nullptr; const u16* pb1 = nullptr;
  int rowB[2], ohsB[2], owsB[2];
  int q = 0, cnt = 0, khs = 0, kws = 0;
#pragma unroll
  for (int j = 0; j < 2; ++j) {
    int n = n0 + wid * 32 + j * 16 + srow;
    int b = n >> l2ohow, p = n & ((1 << l2ohow) - 1);
    int oh = p >> l2ow, ow = p & ((1 << l2ow) - 1);
    if (QDIV == 1) {
      const u16* gg = X + ((size_t)(b * Hp + oh + ipad) * Hp + (ow + ipad)) * C + kb + schunk * 8;
      if (j == 0) pb0 = gg; else pb1 = gg;
    } else if (QDIV == 5) {
      rowB[j] = n;
    } else {
      rowB[j] = b * Hp; ohsB[j] = oh * STR + ipad; owsB[j] = ow * STR + ipad;
    }
  }
  if (QDIV == 5) {
    q = kb >> l2C;
    int c0 = kb & (C - 1);
    cnt = (C - c0) >> 5;
    const u16* base = (q < 4) ? (X + (((size_t)q << Hp) << l2C)) : X2;
    pb0 = base + (((size_t)rowB[0]) << l2C) + c0 + schunk * 8;
    pb1 = base + (((size_t)rowB[1]) << l2C) + c0 + schunk * 8;
  } else if (QDIV != 1) {
    q = kb >> l2C;
    int c0 = kb & (C - 1);
    cnt = (C - c0) >> 5;
    if (QDIV == 4) { khs = q >> 1; kws = q & 1; } else { khs = q / 3; kws = q - khs * 3; }
    pb0 = X + ((size_t)(rowB[0] + ohsB[0] + khs) * Hp + (owsB[0] + kws)) * C + c0 + schunk * 8;
    pb1 = X + ((size_t)(rowB[1] + ohsB[1] + khs) * Hp + (owsB[1] + kws)) * C + c0 + schunk * 8;
  }

  f4v acc[2][4];
#pragma unroll
  for (int i = 0; i < 2; ++i)
#pragma unroll
    for (int j = 0; j < 4; ++j) acc[i][j] = (f4v){0.f, 0.f, 0.f, 0.f};

  const int fr = lane & 15, kc = lane >> 4;
  const int fxor = (kc ^ ((fr >> 1) & 3)) * 8;

  auto advB = [&]() {
    if (QDIV == 1) { pb0 += 32; pb1 += 32; }
    else if (--cnt == 0) {
      ++q; cnt = C >> 5;
      if (QDIV == 5) {
        const u16* base = (q < 4) ? (X + (((size_t)q << Hp) << l2C)) : X2;
        pb0 = base + (((size_t)rowB[0]) << l2C) + schunk * 8;
        pb1 = base + (((size_t)rowB[1]) << l2C) + schunk * 8;
      } else {
        if (++kws == KW) { kws = 0; ++khs; }
        pb0 = X + ((size_t)(rowB[0] + ohsB[0] + khs) * Hp + (owsB[0] + kws)) * C + schunk * 8;
        pb1 = X + ((size_t)(rowB[1] + ohsB[1] + khs) * Hp + (owsB[1] + kws)) * C + schunk * 8;
      }
    } else { pb0 += 32; pb1 += 32; }
  };
  auto stage = [&](int buf) {
    u16* la = Al + buf * 2048 + wid * 512;
    u16* lb = Bl + buf * 4096 + wid * 1024;
    gload16(pa0, la);
    gload16(pb0, lb); gload16(pb1, lb + 512);
    pa0 += 32;
    advB();
  };

  const int nt = Ksp >> 5;
  stage(0);
  for (int t = 0; t < nt; ++t) {
    const int cur = t & 1;
    if (t + 1 < nt) {
      stage(cur ^ 1);
      asm volatile("s_waitcnt vmcnt(3)" ::: "memory");
    } else {
      asm volatile("s_waitcnt vmcnt(0)" ::: "memory");
    }
    __builtin_amdgcn_s_barrier();
    asm volatile("" ::: "memory");
    const u16* ca = Al + cur * 2048;
    const u16* cb = Bl + cur * 4096;
    s8v a[2], bv[4];
#pragma unroll
    for (int mf = 0; mf < 2; ++mf) a[mf] = *(const s8v*)&ca[(mw + mf * 16 + fr) * 32 + fxor];
#pragma unroll
    for (int nf = 0; nf < 4; ++nf) bv[nf] = *(const s8v*)&cb[(nw + nf * 16 + fr) * 32 + fxor];
#pragma unroll
    for (int mf = 0; mf < 2; ++mf)
#pragma unroll
      for (int nf = 0; nf < 4; ++nf)
        acc[mf][nf] = __builtin_amdgcn_mfma_f32_16x16x32_bf16(a[mf], bv[nf], acc[mf][nf], 0, 0, 0);
    __builtin_amdgcn_s_barrier();
    asm volatile("" ::: "memory");
  }

  const int r4 = kc * 4;
  if (FUSE) {
    // direct per-fragment epilogue (r13 path)
    float g = ep.gmode ? *ep.gamma : 0.f;
#pragma unroll
    for (int nf = 0; nf < 4; ++nf) {
      int n = n0 + nw + nf * 16 + fr;
      int b = n >> l2ohow, p = n & ((1 << l2ohow) - 1);
      int oh = p >> l2ow, ow = p & ((1 << l2ow) - 1);
#pragma unroll
      for (int mf = 0; mf < 2; ++mf)
        epi4(acc[mf][nf], m0 + mw + mf * 16 + r4, b, oh, ow, p, M, l2ohow, g, ep);
    }
  } else {
    // LDS-transposed m-inner [z][N][M] float4 write-out (r14 path)
#pragma unroll
    for (int nf = 0; nf < 4; ++nf) {
      int pl = nw + nf * 16 + fr;
#pragma unroll
      for (int mf = 0; mf < 2; ++mf)
        *(f4v*)&Cl[pl * 68 + mw + mf * 16 + r4] = acc[mf][nf];
    }
    __builtin_amdgcn_s_barrier();
    asm volatile("" ::: "memory");
    const int ml2 = (tid & 15) << 2;
    const int prow = tid >> 4;
#pragma unroll
    for (int pass = 0; pass < 8; ++pass) {
      int pl = pass * 16 + prow;
      int n = n0 + pl;
      *(f4v*)&part[((size_t)blockIdx.z * N + n) * M + m0 + ml2] =
          *(const f4v*)&Cl[pl * 68 + ml2];
    }
  }
}

// ---------------------------------------------------------------------------
// Split-K reduce + epilogue, m-inner coalesced. part: [z][N][M] fp32.
// ---------------------------------------------------------------------------
__global__ __launch_bounds__(256)
void k_red2(const float* __restrict__ part, int z, int l2N, int l2M4, int M,
            int l2ohow, int l2ow, Epi ep) {
  const size_t total = (size_t)1 << (l2N + l2M4);
  const int N = 1 << l2N;
  float g = ep.gmode ? *ep.gamma : 0.f;
  for (size_t t = (size_t)blockIdx.x * 256 + threadIdx.x; t < total;
       t += (size_t)gridDim.x * 256) {
    int m4 = (int)(t & ((1u << l2M4) - 1));
    int n = (int)(t >> l2M4);
    int m = m4 << 2;
    f4v v = (f4v){0.f, 0.f, 0.f, 0.f};
    for (int s = 0; s < z; ++s) {
      f4v x = *(const f4v*)&part[((size_t)s * N + n) * M + m];
      v = v + x;
    }
    int b = n >> l2ohow, p = n & ((1 << l2ohow) - 1);
    int oh = p >> l2ow, ow = p & ((1 << l2ow) - 1);
    epi4(v, m, b, oh, ow, p, M, l2ohow, g, ep);
  }
}

// ---------------------------------------------------------------------------
// ws layout (u16 element offsets). Total 110,100,480 u16 = 220.2 MB.
// ---------------------------------------------------------------------------
static const size_t WR_BA3 = 0, WR_BA4 = 327680, WR_BA5 = 1638400,
  WR_P51 = 6881280, WR_P51D = 7143424, WR_P52 = 7405568, WR_P41 = 7995392,
  WR_P41D = 8126464, WR_P42 = 8257536, WR_P31 = 8847360, WR_P31D = 8912896,
  WR_P32 = 8978432, WR_P6 = 9568256, WR_P7 = 11927552, WR_C34 = 12517376,
  WR_C45 = 13107200, WR_C35 = 13369344;
static const size_t O_C3N = 13631488, O_C4N = 22020096, O_C5N = 26214400,
  O_C3BA = 28311552, O_C4BA = 36700160, O_C5BA = 40894464,
  O_CAT = 42991616, O_SCR = 76546048;
static const size_t O_P3D = O_CAT, O_P3PRE = O_CAT + 8921088,
  O_P4PRE = O_CAT + 17842176, O_P3D1 = O_CAT + 20209664,
  O_P4D = O_CAT + 22306816, O_P4D1 = O_CAT + 24403968,
  O_P3D2 = O_CAT + 24928256, O_P5PRE = O_CAT + 25452544,
  O_P5S = O_CAT + 26116096, O_P6R = O_CAT + 26640384, O_C5P = O_CAT + 26845184;

extern "C" void kernel_launch(void* const* d_in, const int* in_sizes, int n_in,
                              void* d_out, int out_size, void* d_ws, size_t ws_size,
                              hipStream_t stream) {
  (void)in_sizes; (void)n_in; (void)out_size; (void)ws_size;
  const float* C3 = (const float*)d_in[0];
  const float* C4 = (const float*)d_in[1];
  const float* C5 = (const float*)d_in[2];
  const float* ba3_w = (const float*)d_in[3];  const float* ba3_b = (const float*)d_in[4];
  const float* ba4_w = (const float*)d_in[5];  const float* ba4_b = (const float*)d_in[6];
  const float* ba5_w = (const float*)d_in[7];  const float* ba5_b = (const float*)d_in[8];
  const float* p5_1_w = (const float*)d_in[9];  const float* p5_1_b = (const float*)d_in[10];
  const float* p5_1d_w = (const float*)d_in[11]; const float* p5_1d_b = (const float*)d_in[12];
  const float* p5_2_w = (const float*)d_in[13]; const float* p5_2_b = (const float*)d_in[14];
  const float* p4_1_w = (const float*)d_in[15]; const float* p4_1_b = (const float*)d_in[16];
  const float* p4_1d_w = (const float*)d_in[17]; const float* p4_1d_b = (const float*)d_in[18];
  const float* p4_2_w = (const float*)d_in[19]; const float* p4_2_b = (const float*)d_in[20];
  const float* p3_1_w = (const float*)d_in[21]; const float* p3_1_b = (const float*)d_in[22];
  const float* p3_1d_w = (const float*)d_in[23]; const float* p3_1d_b = (const float*)d_in[24];
  const float* p3_2_w = (const float*)d_in[25]; const float* p3_2_b = (const float*)d_in[26];
  const float* p6_w = (const float*)d_in[27]; const float* p6_b = (const float*)d_in[28];
  const float* p7_w = (const float*)d_in[29]; const float* p7_b = (const float*)d_in[30];
  const float* c34_w = (const float*)d_in[31]; const float* c34_b = (const float*)d_in[32];
  const float* c45_w = (const float*)d_in[33]; const float* c45_b = (const float*)d_in[34];
  const float* c35_w = (const float*)d_in[35]; const float* c35_b = (const float*)d_in[36];
  const float* g3 = (const float*)d_in[37];
  const float* g4 = (const float*)d_in[38];
  const float* g5 = (const float*)d_in[39];

  float* out = (float*)d_out;
  float* O3 = out;
  float* O4 = out + 8388608;
  float* O5 = out + 10485760;
  float* P6o = out + 11010048;
  float* P7o = out + 11141120;

  u16* wsu = (u16*)d_ws;
  u16* c3n = wsu + O_C3N;  u16* c4n = wsu + O_C4N;  u16* c5n = wsu + O_C5N;
  u16* c3ba = wsu + O_C3BA; u16* c4ba = wsu + O_C4BA; u16* c5ba = wsu + O_C5BA;
  u16* catb = wsu + O_CAT;
  u16* scr = wsu + O_SCR;
  u16* p3d = wsu + O_P3D;  u16* p3d1 = wsu + O_P3D1; u16* p3d2 = wsu + O_P3D2;
  u16* p4d = wsu + O_P4D;  u16* p4d1 = wsu + O_P4D1;
  u16* p5pre = wsu + O_P5PRE; u16* p5s = wsu + O_P5S; u16* p4pre = wsu + O_P4PRE;
  u16* p3pre = wsu + O_P3PRE; u16* p6r = wsu + O_P6R; u16* c5p = wsu + O_C5P;
  float* part = (float*)scr;
  float* partba = (float*)scr;

  const Epi enone = {nullptr, nullptr,0,0,0, nullptr,0,0,0, nullptr,nullptr,0,0,0, nullptr,0,0,0, nullptr};

  // ---- weight conversion ----
  WTab tab;
  int ti = 0, blk = 0;
  auto add = [&](const float* s, size_t off, int M, int K, int l2Cin, int mode) {
    int kt = (K + 255) / 256;
    tab.s[ti].src = s; tab.s[ti].dst = wsu + off; tab.s[ti].K = K;
    tab.s[ti].l2Cin = l2Cin; tab.s[ti].mode = mode;
    tab.s[ti].ktiles = kt; tab.s[ti].blk0 = blk;
    blk += M * kt; ++ti;
  };
  add(ba3_w, WR_BA3, 256, 1280, 8, 1);
  add(ba4_w, WR_BA4, 512, 2560, 9, 1);
  add(ba5_w, WR_BA5, 1024, 5120, 10, 1);
  add(p5_1_w, WR_P51, 256, 1024, 10, 0);
  add(p5_1d_w, WR_P51D, 256, 1024, 10, 0);
  add(p5_2_w, WR_P52, 256, 2304, 8, 0);
  add(p4_1_w, WR_P41, 256, 512, 9, 0);
  add(p4_1d_w, WR_P41D, 256, 512, 9, 0);
  add(p4_2_w, WR_P42, 256, 2304, 8, 0);
  add(p3_1_w, WR_P31, 256, 256, 8, 0);
  add(p3_1d_w, WR_P31D, 256, 256, 8, 0);
  add(p3_2_w, WR_P32, 256, 2304, 8, 0);
  add(p6_w, WR_P6, 256, 9216, 10, 0);
  add(p7_w, WR_P7, 256, 2304, 8, 0);
  add(c34_w, WR_C34, 256, 2304, 8, 0);
  add(c45_w, WR_C45, 256, 1024, 8, 0);
  add(c35_w, WR_C35, 256, 1024, 8, 0);
  k_cvt_w<<<blk, 256, 0, stream>>>(tab);

  // ---- input NHWC conversions ----
  k_cvt_x<<<dim3(16,64,8), 256, 0, stream>>>(C3, c3n, 256, 64, 64, 64, 0, 2);
  k_cvt_x<<<dim3(16,32,8), 256, 0, stream>>>(C4, c4n, 512, 32, 32, 32, 0, 1);
  k_cvt_x<<<dim3(32,16,8), 256, 0, stream>>>(C5, c5n, 1024, 16, 16, 16, 0, 1);

  // ================= BA phase (NHWC-direct scans) =================
  {
    const size_t GS3 = 8388608;
    k_scanH<<<dim3(128,2), 256, 0, stream>>>(c3n, catb, catb + GS3, 64, 256);
    k_scanW<<<dim3(128,2), 256, 0, stream>>>(c3n, catb + 2*GS3, catb + 3*GS3, 64, 256);
    Epi ep = {ba3_b, nullptr,0,0,0, nullptr,0,0,0, nullptr,nullptr,0,0,0, c3ba,64,0,0, nullptr};
    k_gemm<5,1,1,true><<<dim3(256,4,1), 256, 0, stream>>>(
        catb, c3n, wsu + WR_BA3, nullptr, 256, 8, 15, 0, 12, 6, 1280, 1280, 256, 32768, ep);
  }
  {
    const size_t GS4 = 4194304;
    k_scanH<<<dim3(128,2), 256, 0, stream>>>(c4n, catb, catb + GS4, 32, 512);
    k_scanW<<<dim3(128,2), 256, 0, stream>>>(c4n, catb + 2*GS4, catb + 3*GS4, 32, 512);
    k_gemm<5,1,1,false><<<dim3(64,8,2), 256, 0, stream>>>(
        catb, c4n, wsu + WR_BA4, partba, 512, 9, 13, 0, 10, 5, 2560, 1280, 512, 8192, enone);
    Epi ep = {ba4_b, nullptr,0,0,0, nullptr,0,0,0, nullptr,nullptr,0,0,0, c4ba,32,0,0, nullptr};
    k_red2<<<2048, 256, 0, stream>>>(partba, 2, 13, 7, 512, 10, 5, ep);
  }
  {
    const size_t GS5 = 2097152;
    k_scanH<<<dim3(128,2), 256, 0, stream>>>(c5n, catb, catb + GS5, 16, 1024);
    k_scanW<<<dim3(128,2), 256, 0, stream>>>(c5n, catb + 2*GS5, catb + 3*GS5, 16, 1024);
    k_gemm<5,1,1,false><<<dim3(16,16,4), 256, 0, stream>>>(
        catb, c5n, wsu + WR_BA5, partba, 1024, 10, 11, 0, 8, 4, 5120, 1280, 1024, 2048, enone);
    Epi ep = {ba5_b, nullptr,0,0,0, nullptr,0,0,0, nullptr,nullptr,0,0,0, c5ba,16,0,0, nullptr};
    k_red2<<<2048, 256, 0, stream>>>(partba, 4, 11, 8, 1024, 8, 4, ep);
  }

  // ---- CAT area free: zero padded persistents, build c5p ----
  hipMemsetAsync(p3d, 0, (size_t)8921088 * 2, stream);
  hipMemsetAsync(p3pre, 0, (size_t)8921088 * 2, stream);
  hipMemsetAsync(p4pre, 0, (size_t)2367488 * 2, stream);
  hipMemsetAsync(p5pre, 0, (size_t)663552 * 2, stream);
  hipMemsetAsync(p6r, 0, (size_t)204800 * 2, stream);
  hipMemsetAsync(c5p, 0, (size_t)2654208 * 2, stream);
  k_cvt_x<<<dim3(32,16,8), 256, 0, stream>>>(C5, c5p, 1024, 16, 16, 18, 1, 1);

  // ================= dual (bottom-up) path =================
  {
    Epi ep = {p3_1d_b, nullptr,0,0,0, nullptr,0,0,0, nullptr,nullptr,0,0,0, p3d,66,1,0, nullptr};
    k_gemm<1,1,1,true><<<dim3(256,4,1), 256, 0, stream>>>(
        c3ba, nullptr, wsu + WR_P31D, nullptr, 256, 0, 64, 0, 12, 6, 256, 256, 256, 32768, ep);
  }
  k_gemm<9,3,2,false><<<dim3(64,4,4), 256, 0, stream>>>(
      p3d, nullptr, wsu + WR_C34, part, 256, 8, 66, 0, 10, 5, 2304, 576, 256, 8192, enone);
  {
    Epi ep = {c34_b, nullptr,0,0,0, nullptr,0,0,0, nullptr,nullptr,0,0,0, p3d1,32,0,0, nullptr};
    k_red2<<<2048, 256, 0, stream>>>(part, 4, 13, 6, 256, 10, 5, ep);
  }
  k_gemm<4,2,2,false><<<dim3(16,4,8), 256, 0, stream>>>(
      p3d1, nullptr, wsu + WR_C35, part, 256, 8, 32, 0, 8, 4, 1024, 128, 256, 2048, enone);
  {
    Epi ep = {c35_b, nullptr,0,0,0, nullptr,0,0,0, nullptr,nullptr,0,0,0, p3d2,16,0,0, nullptr};
    k_red2<<<2048, 256, 0, stream>>>(part, 8, 11, 6, 256, 8, 4, ep);
  }
  k_gemm<1,1,1,false><<<dim3(64,4,4), 256, 0, stream>>>(
      c4ba, nullptr, wsu + WR_P41D, part, 512, 0, 32, 0, 10, 5, 512, 128, 256, 8192, enone);
  {
    Epi ep = {p4_1d_b, p3d1,32,0,0, nullptr,0,0,0, nullptr,nullptr,0,0,0, p4d,32,0,0, nullptr};
    k_red2<<<2048, 256, 0, stream>>>(part, 4, 13, 6, 256, 10, 5, ep);
  }
  k_gemm<4,2,2,false><<<dim3(16,4,8), 256, 0, stream>>>(
      p4d, nullptr, wsu + WR_C45, part, 256, 8, 32, 0, 8, 4, 1024, 128, 256, 2048, enone);
  {
    Epi ep = {c45_b, nullptr,0,0,0, nullptr,0,0,0, nullptr,nullptr,0,0,0, p4d1,16,0,0, nullptr};
    k_red2<<<2048, 256, 0, stream>>>(part, 8, 11, 6, 256, 8, 4, ep);
  }

  // ================= top-down path =================
  k_gemm<1,1,1,false><<<dim3(16,4,8), 256, 0, stream>>>(
      c5n, nullptr, wsu + WR_P51, part, 1024, 0, 16, 0, 8, 4, 1024, 128, 256, 2048, enone);
  {
    Epi ep = {p5_1_b, nullptr,0,0,0, nullptr,0,0,0, nullptr,nullptr,0,0,0, p5pre,18,1,0, nullptr};
    k_red2<<<2048, 256, 0, stream>>>(part, 8, 11, 6, 256, 8, 4, ep);
  }
  k_gemm<9,3,1,false><<<dim3(16,4,8), 256, 0, stream>>>(
      p5pre, nullptr, wsu + WR_P52, part, 256, 8, 18, 0, 8, 4, 2304, 288, 256, 2048, enone);
  {
    Epi ep = {p5_2_b, nullptr,0,0,0, nullptr,0,0,0, nullptr,nullptr,0,0,0, p5s,16,0,0, nullptr};
    k_red2<<<2048, 256, 0, stream>>>(part, 8, 11, 6, 256, 8, 4, ep);
  }
  k_gemm<1,1,1,false><<<dim3(64,4,4), 256, 0, stream>>>(
      c4n, nullptr, wsu + WR_P41, part, 512, 0, 32, 0, 10, 5, 512, 128, 256, 8192, enone);
  {
    Epi ep = {p4_1_b, p5pre,18,1,1, nullptr,0,0,0, nullptr,nullptr,0,0,0, p4pre,34,1,0, nullptr};
    k_red2<<<2048, 256, 0, stream>>>(part, 4, 13, 6, 256, 10, 5, ep);
  }
  k_gemm<9,3,1,false><<<dim3(64,4,4), 256, 0, stream>>>(
      p4pre, nullptr, wsu + WR_P42, part, 256, 8, 34, 0, 10, 5, 2304, 576, 256, 8192, enone);
  {
    Epi ep = {p4_2_b, nullptr,0,0,0, nullptr,0,0,0, g4,p4d,32,0,1, nullptr,0,0,0, O4};
    k_red2<<<2048, 256, 0, stream>>>(part, 4, 13, 6, 256, 10, 5, ep);
  }
  {
    Epi ep = {p3_1_b, p4pre,34,1,1, p5pre,18,1,2, nullptr,nullptr,0,0,0, p3pre,66,1,0, nullptr};
    k_gemm<1,1,1,true><<<dim3(256,4,1), 256, 0, stream>>>(
        c3n, nullptr, wsu + WR_P31, nullptr, 256, 0, 64, 0, 12, 6, 256, 256, 256, 32768, ep);
  }
  {
    Epi ep = {p3_2_b, nullptr,0,0,0, nullptr,0,0,0, g3,p3d,66,1,1, nullptr,0,0,0, O3};
    k_gemm<9,3,1,true><<<dim3(256,4,1), 256, 0, stream>>>(
        p3pre, nullptr, wsu + WR_P32, nullptr, 256, 8, 66, 0, 12, 6, 2304, 2304, 256, 32768, ep);
  }
  k_gemm<1,1,1,false><<<dim3(16,4,8), 256, 0, stream>>>(
      c5ba, nullptr, wsu + WR_P51D, part, 1024, 0, 16, 0, 8, 4, 1024, 128, 256, 2048, enone);
  {
    Epi ep = {p5_1d_b, p4d1,16,0,0, p3d2,16,0,0, g5,p5s,16,0,2, nullptr,0,0,0, O5};
    k_red2<<<2048, 256, 0, stream>>>(part, 8, 11, 6, 256, 8, 4, ep);
  }

  // ================= P6 / P7 =================
  k_gemm<9,3,2,false><<<dim3(4,4,32), 256, 0, stream>>>(
      c5p, nullptr, wsu + WR_P6, part, 1024, 10, 18, 0, 6, 3, 9216, 288, 256, 512, enone);
  {
    Epi ep = {p6_b, nullptr,0,0,0, nullptr,0,0,0, nullptr,nullptr,0,0,0, p6r,10,1,1, P6o};
    k_red2<<<512, 256, 0, stream>>>(part, 32, 9, 6, 256, 6, 3, ep);
  }
  k_gemm<9,3,2,false><<<dim3(1,4,8), 256, 0, stream>>>(
      p6r, nullptr, wsu + WR_P7, part, 256, 8, 10, 0, 4, 2, 2304, 288, 256, 128, enone);
  {
    Epi ep = {p7_b, nullptr,0,0,0, nullptr,0,0,0, nullptr,nullptr,0,0,0, nullptr,0,0,0, P7o};
    k_red2<<<128, 256, 0, stream>>>(part, 8, 7, 6, 256, 4, 2, ep);
  }
}